// Round 1
// baseline (1740.340 us; speedup 1.0000x reference)
//
#include <hip/hip_runtime.h>
#include <math.h>

#define NN 100000
#define EE 3200000
#define ET 3300000   // EE + NN self loops
#define FIN 512
#define HDIM 64
#define NCLS 40

// ---------------- CSR build ----------------
__global__ void k_init_cnt(int* cnt){
  int i = blockIdx.x*256 + threadIdx.x;
  if(i < NN) cnt[i] = 1;   // self loop counted up front
}

__global__ void k_hist(const int* __restrict__ dst, int* __restrict__ cnt){
  int e = blockIdx.x*256 + threadIdx.x;
  if(e < EE) atomicAdd(&cnt[dst[e]], 1);
}

// block scans 1024 elements (256 threads x 4), writes block-exclusive prefix + block sum
__global__ void k_scan1(const int* __restrict__ cnt, int* __restrict__ rp, int* __restrict__ bsum){
  __shared__ int lds[256];
  int t = threadIdx.x, b = blockIdx.x;
  int base = b*1024 + t*4;
  int v[4];
  #pragma unroll
  for(int j=0;j<4;j++) v[j] = (base+j < NN) ? cnt[base+j] : 0;
  int tsum = v[0]+v[1]+v[2]+v[3];
  lds[t] = tsum;
  __syncthreads();
  for(int off=1; off<256; off<<=1){
    int x = 0;
    if(t >= off) x = lds[t-off];
    __syncthreads();
    if(t >= off) lds[t] += x;
    __syncthreads();
  }
  int excl = lds[t] - tsum;
  if(t == 255) bsum[b] = lds[255];
  int run = excl;
  #pragma unroll
  for(int j=0;j<4;j++){
    if(base+j < NN) rp[base+j] = run;
    run += v[j];
  }
}

__global__ void k_scan2(int* bsum){  // 1 block, 128 threads, 98 valid
  __shared__ int lds[128];
  int t = threadIdx.x;
  int v = (t < 98) ? bsum[t] : 0;
  lds[t] = v;
  __syncthreads();
  for(int off=1; off<128; off<<=1){
    int x = 0;
    if(t >= off) x = lds[t-off];
    __syncthreads();
    if(t >= off) lds[t] += x;
    __syncthreads();
  }
  if(t < 98) bsum[t] = lds[t] - v;  // exclusive
}

__global__ void k_add(int* __restrict__ rp, int* __restrict__ cursor, const int* __restrict__ bsum){
  int i = blockIdx.x*256 + threadIdx.x;
  if(i < NN){
    int r = rp[i] + bsum[i>>10];
    rp[i] = r;
    cursor[i] = r;
  }
  if(i == 0) rp[NN] = ET;
}

__global__ void k_scatter(const int* __restrict__ src, const int* __restrict__ dst,
                          int* __restrict__ cursor, int* __restrict__ col){
  int e = blockIdx.x*256 + threadIdx.x;
  if(e >= ET) return;
  int s, d;
  if(e < EE){ s = src[e]; d = dst[e]; }
  else { s = e - EE; d = s; }
  int pos = atomicAdd(&cursor[d], 1);
  col[pos] = s;
}

// ---------------- tiled f32 GEMM: Out[M x C] = A[M x K] @ W[K x C], C <= 64 ----------------
template<int K, int C>
__global__ __launch_bounds__(256) void k_gemm(const float* __restrict__ A, const float* __restrict__ W,
                                              float* __restrict__ Out, int M){
  __shared__ float As[64][68];
  __shared__ float Ws[64][68];
  int t = threadIdx.x;
  int row0 = blockIdx.x * 64;
  float acc[4][4] = {{0.f}};
  int tr = (t >> 4) * 4;      // 0..60
  int tc = (t & 15) * 4;      // 0..60
  int arow = t >> 2;          // 0..63
  int acol = (t & 3) * 16;    // 0,16,32,48

  for(int kc = 0; kc < K; kc += 64){
    int rg = row0 + arow; if(rg >= M) rg = M-1;
    #pragma unroll
    for(int j=0;j<4;j++){
      *(float4*)&As[arow][acol + 4*j] = *(const float4*)&A[(size_t)rg*K + kc + acol + 4*j];
    }
    #pragma unroll
    for(int j=0;j<16;j++){
      int c = acol + j;
      Ws[arow][c] = (c < C) ? W[(kc + arow)*C + c] : 0.f;
    }
    __syncthreads();
    for(int kk=0; kk<64; kk+=4){
      float4 A4[4], W4[4];
      #pragma unroll
      for(int i=0;i<4;i++) A4[i] = *(float4*)&As[tr+i][kk];
      #pragma unroll
      for(int q=0;q<4;q++) W4[q] = *(float4*)&Ws[kk+q][tc];
      #pragma unroll
      for(int i=0;i<4;i++){
        float4 a = A4[i];
        acc[i][0] += a.x*W4[0].x + a.y*W4[1].x + a.z*W4[2].x + a.w*W4[3].x;
        acc[i][1] += a.x*W4[0].y + a.y*W4[1].y + a.z*W4[2].y + a.w*W4[3].y;
        acc[i][2] += a.x*W4[0].z + a.y*W4[1].z + a.z*W4[2].z + a.w*W4[3].z;
        acc[i][3] += a.x*W4[0].w + a.y*W4[1].w + a.z*W4[2].w + a.w*W4[3].w;
      }
    }
    __syncthreads();
  }
  #pragma unroll
  for(int i=0;i<4;i++){
    int r = row0 + tr + i;
    if(r >= M) continue;
    #pragma unroll
    for(int j=0;j<4;j++){
      int c = tc + j;
      if(c < C) Out[(size_t)r*C + c] = acc[i][j];
    }
  }
}

// ---------------- per-node attention coefficients ----------------
template<int HEADS, int DIM>
__global__ void k_att(const float* __restrict__ h, const float* __restrict__ a_src,
                      const float* __restrict__ a_dst, float* __restrict__ as_o, float* __restrict__ ad_o){
  int gid = blockIdx.x*256 + threadIdx.x;
  int node = gid >> 6, lane = gid & 63;
  if(node >= NN) return;
  constexpr int HD = HEADS*DIM;
  float v = 0.f, asc = 0.f, adc = 0.f;
  if(lane < HD){ v = h[(size_t)node*HD + lane]; asc = a_src[lane]; adc = a_dst[lane]; }
  float s1 = v*asc, s2 = v*adc;
  if(HEADS == 8){
    #pragma unroll
    for(int m=1;m<8;m<<=1){ s1 += __shfl_xor(s1,m); s2 += __shfl_xor(s2,m); }
    if((lane & 7) == 0){ as_o[node*8 + (lane>>3)] = s1; ad_o[node*8 + (lane>>3)] = s2; }
  } else {
    #pragma unroll
    for(int m=1;m<64;m<<=1){ s1 += __shfl_xor(s1,m); s2 += __shfl_xor(s2,m); }
    if(lane == 0){ as_o[node] = s1; ad_o[node] = s2; }
  }
}

// ---------------- aggregation: online segment softmax + weighted sum ----------------
template<int HEADS, int DIM, bool DO_ELU, bool DO_LSM>
__global__ void k_agg(const float* __restrict__ hprev, const int* __restrict__ rp, const int* __restrict__ col,
                      const float* __restrict__ as_, const float* __restrict__ ad_,
                      const float* __restrict__ bias, float* __restrict__ out){
  int gid = blockIdx.x*256 + threadIdx.x;
  int node = gid >> 6, lane = gid & 63;
  if(node >= NN) return;
  constexpr int HD = HEADS*DIM;
  bool act = lane < HD;
  int hidx = act ? lane / DIM : 0;
  int beg = rp[node], end = rp[node+1];
  float adn = ad_[node*HEADS + hidx];
  float m = -INFINITY, s = 0.f, acc = 0.f;
  for(int i=beg; i<end; i++){
    int srcn = col[i];
    float e = as_[srcn*HEADS + hidx] + adn;
    e = (e > 0.f) ? e : 0.2f*e;
    float mn = fmaxf(m, e);
    float c = __expf(m - mn);
    float p = __expf(e - mn);
    s = s*c + p;
    float hv = act ? hprev[(size_t)srcn*HD + lane] : 0.f;
    acc = acc*c + p*hv;
    m = mn;
  }
  float o = acc/s + (act ? bias[lane] : 0.f);
  if(DO_ELU) o = (o > 0.f) ? o : expm1f(o);
  if(!DO_LSM){
    if(act) out[(size_t)node*HD + lane] = o;
  } else {
    float vmax = act ? o : -INFINITY;
    #pragma unroll
    for(int mm=1; mm<64; mm<<=1) vmax = fmaxf(vmax, __shfl_xor(vmax, mm));
    float ex = act ? expf(o - vmax) : 0.f;
    #pragma unroll
    for(int mm=1; mm<64; mm<<=1) ex += __shfl_xor(ex, mm);
    float res = o - vmax - logf(ex);
    if(act) out[(size_t)node*HD + lane] = res;
  }
}

// ---------------- launch ----------------
static inline size_t alignup(size_t x){ return (x + 255) & ~(size_t)255; }

extern "C" void kernel_launch(void* const* d_in, const int* in_sizes, int n_in,
                              void* d_out, int out_size, void* d_ws, size_t ws_size,
                              hipStream_t stream){
  const float* x      = (const float*)d_in[0];
  const int*   ei     = (const int*)d_in[1];
  const float* W1     = (const float*)d_in[2];
  const float* asrc1  = (const float*)d_in[3];
  const float* adst1  = (const float*)d_in[4];
  const float* b1     = (const float*)d_in[5];
  const float* W2     = (const float*)d_in[6];
  const float* asrc2  = (const float*)d_in[7];
  const float* adst2  = (const float*)d_in[8];
  const float* b2     = (const float*)d_in[9];
  const float* W3     = (const float*)d_in[10];
  const float* asrc3  = (const float*)d_in[11];
  const float* adst3  = (const float*)d_in[12];
  const float* b3     = (const float*)d_in[13];
  const int* src = ei;
  const int* dst = ei + EE;

  char* w = (char*)d_ws;
  int* cursor = (int*)w;              w += alignup((size_t)NN*4);
  int* rp     = (int*)w;              w += alignup((size_t)(NN+1)*4);
  int* bsum   = (int*)w;              w += alignup(512);
  int* col    = (int*)w;              w += alignup((size_t)ET*4);
  float* hA   = (float*)w;            w += alignup((size_t)NN*HDIM*4);
  float* hB   = (float*)w;            w += alignup((size_t)NN*HDIM*4);
  float* hC   = (float*)w;            w += alignup((size_t)NN*NCLS*4);
  float* asA  = (float*)w;            w += alignup((size_t)NN*8*4);
  float* adA  = (float*)w;            w += alignup((size_t)NN*8*4);

  dim3 blk(256);
  int gN   = (NN + 255)/256;
  int gE   = (EE + 255)/256;
  int gET  = (ET + 255)/256;
  int gWav = (NN*64 + 255)/256;   // wave per node
  int gGemm = (NN + 63)/64;

  // CSR
  k_init_cnt<<<gN, blk, 0, stream>>>(cursor);
  k_hist<<<gE, blk, 0, stream>>>(dst, cursor);
  k_scan1<<<98, blk, 0, stream>>>(cursor, rp, bsum);
  k_scan2<<<1, dim3(128), 0, stream>>>(bsum);
  k_add<<<gN, blk, 0, stream>>>(rp, cursor, bsum);
  k_scatter<<<gET, blk, 0, stream>>>(src, dst, cursor, col);

  // layer 1
  k_gemm<FIN, HDIM><<<gGemm, blk, 0, stream>>>(x, W1, hA, NN);
  k_att<8,8><<<gWav, blk, 0, stream>>>(hA, asrc1, adst1, asA, adA);
  k_agg<8,8,true,false><<<gWav, blk, 0, stream>>>(hA, rp, col, asA, adA, b1, hB);

  // layer 2
  k_gemm<HDIM, HDIM><<<gGemm, blk, 0, stream>>>(hB, W2, hA, NN);
  k_att<8,8><<<gWav, blk, 0, stream>>>(hA, asrc2, adst2, asA, adA);
  k_agg<8,8,true,false><<<gWav, blk, 0, stream>>>(hA, rp, col, asA, adA, b2, hB);

  // layer 3
  k_gemm<HDIM, NCLS><<<gGemm, blk, 0, stream>>>(hB, W3, hC, NN);
  k_att<1,NCLS><<<gWav, blk, 0, stream>>>(hC, asrc3, adst3, asA, adA);
  k_agg<1,NCLS,false,true><<<gWav, blk, 0, stream>>>(hC, rp, col, asA, adA, b3, (float*)d_out);
}

// Round 2
// 1175.101 us; speedup vs baseline: 1.4810x; 1.4810x over previous
//
#include <hip/hip_runtime.h>
#include <math.h>

#define NN 100000
#define EE 3200000
#define ET 3300000   // EE + NN self loops
#define FIN 512
#define HDIM 64
#define NCLS 40

// ---------------- CSR build ----------------
__global__ void k_init_cnt(int* cnt){
  int i = blockIdx.x*256 + threadIdx.x;
  if(i < NN) cnt[i] = 1;   // self loop counted up front
}

__global__ void k_hist(const int* __restrict__ dst, int* __restrict__ cnt){
  int e = blockIdx.x*256 + threadIdx.x;
  if(e < EE) atomicAdd(&cnt[dst[e]], 1);
}

// block scans 1024 elements (256 threads x 4), writes block-exclusive prefix + block sum
__global__ void k_scan1(const int* __restrict__ cnt, int* __restrict__ rp, int* __restrict__ bsum){
  __shared__ int lds[256];
  int t = threadIdx.x, b = blockIdx.x;
  int base = b*1024 + t*4;
  int v[4];
  #pragma unroll
  for(int j=0;j<4;j++) v[j] = (base+j < NN) ? cnt[base+j] : 0;
  int tsum = v[0]+v[1]+v[2]+v[3];
  lds[t] = tsum;
  __syncthreads();
  for(int off=1; off<256; off<<=1){
    int x = 0;
    if(t >= off) x = lds[t-off];
    __syncthreads();
    if(t >= off) lds[t] += x;
    __syncthreads();
  }
  int excl = lds[t] - tsum;
  if(t == 255) bsum[b] = lds[255];
  int run = excl;
  #pragma unroll
  for(int j=0;j<4;j++){
    if(base+j < NN) rp[base+j] = run;
    run += v[j];
  }
}

__global__ void k_scan2(int* bsum){  // 1 block, 128 threads, 98 valid
  __shared__ int lds[128];
  int t = threadIdx.x;
  int v = (t < 98) ? bsum[t] : 0;
  lds[t] = v;
  __syncthreads();
  for(int off=1; off<128; off<<=1){
    int x = 0;
    if(t >= off) x = lds[t-off];
    __syncthreads();
    if(t >= off) lds[t] += x;
    __syncthreads();
  }
  if(t < 98) bsum[t] = lds[t] - v;  // exclusive
}

__global__ void k_add(int* __restrict__ rp, int* __restrict__ cursor, const int* __restrict__ bsum){
  int i = blockIdx.x*256 + threadIdx.x;
  if(i < NN){
    int r = rp[i] + bsum[i>>10];
    rp[i] = r;
    cursor[i] = r;
  }
  if(i == 0) rp[NN] = ET;
}

__global__ void k_scatter(const int* __restrict__ src, const int* __restrict__ dst,
                          int* __restrict__ cursor, int* __restrict__ col){
  int e = blockIdx.x*256 + threadIdx.x;
  if(e >= ET) return;
  int s, d;
  if(e < EE){ s = src[e]; d = dst[e]; }
  else { s = e - EE; d = s; }
  int pos = atomicAdd(&cursor[d], 1);
  col[pos] = s;
}

// ---------------- tiled f32 GEMM: Out[M x C] = A[M x K] @ W[K x C], C <= 64 ----------------
template<int K, int C>
__global__ __launch_bounds__(256) void k_gemm(const float* __restrict__ A, const float* __restrict__ W,
                                              float* __restrict__ Out, int M){
  __shared__ float As[64][68];
  __shared__ float Ws[64][68];
  int t = threadIdx.x;
  int row0 = blockIdx.x * 64;
  float acc[4][4] = {{0.f}};
  int tr = (t >> 4) * 4;      // 0..60
  int tc = (t & 15) * 4;      // 0..60
  int arow = t >> 2;          // 0..63
  int acol = (t & 3) * 16;    // 0,16,32,48

  for(int kc = 0; kc < K; kc += 64){
    int rg = row0 + arow; if(rg >= M) rg = M-1;
    #pragma unroll
    for(int j=0;j<4;j++){
      *(float4*)&As[arow][acol + 4*j] = *(const float4*)&A[(size_t)rg*K + kc + acol + 4*j];
    }
    #pragma unroll
    for(int j=0;j<16;j++){
      int c = acol + j;
      Ws[arow][c] = (c < C) ? W[(kc + arow)*C + c] : 0.f;
    }
    __syncthreads();
    for(int kk=0; kk<64; kk+=4){
      float4 A4[4], W4[4];
      #pragma unroll
      for(int i=0;i<4;i++) A4[i] = *(float4*)&As[tr+i][kk];
      #pragma unroll
      for(int q=0;q<4;q++) W4[q] = *(float4*)&Ws[kk+q][tc];
      #pragma unroll
      for(int i=0;i<4;i++){
        float4 a = A4[i];
        acc[i][0] += a.x*W4[0].x + a.y*W4[1].x + a.z*W4[2].x + a.w*W4[3].x;
        acc[i][1] += a.x*W4[0].y + a.y*W4[1].y + a.z*W4[2].y + a.w*W4[3].y;
        acc[i][2] += a.x*W4[0].z + a.y*W4[1].z + a.z*W4[2].z + a.w*W4[3].z;
        acc[i][3] += a.x*W4[0].w + a.y*W4[1].w + a.z*W4[2].w + a.w*W4[3].w;
      }
    }
    __syncthreads();
  }
  #pragma unroll
  for(int i=0;i<4;i++){
    int r = row0 + tr + i;
    if(r >= M) continue;
    #pragma unroll
    for(int j=0;j<4;j++){
      int c = tc + j;
      if(c < C) Out[(size_t)r*C + c] = acc[i][j];
    }
  }
}

// ---------------- per-node attention coefficients ----------------
template<int HEADS, int DIM>
__global__ void k_att(const float* __restrict__ h, const float* __restrict__ a_src,
                      const float* __restrict__ a_dst, float* __restrict__ as_o, float* __restrict__ ad_o){
  int gid = blockIdx.x*256 + threadIdx.x;
  int node = gid >> 6, lane = gid & 63;
  if(node >= NN) return;
  constexpr int HD = HEADS*DIM;
  float v = 0.f, asc = 0.f, adc = 0.f;
  if(lane < HD){ v = h[(size_t)node*HD + lane]; asc = a_src[lane]; adc = a_dst[lane]; }
  float s1 = v*asc, s2 = v*adc;
  if(HEADS == 8){
    #pragma unroll
    for(int m=1;m<8;m<<=1){ s1 += __shfl_xor(s1,m); s2 += __shfl_xor(s2,m); }
    if((lane & 7) == 0){ as_o[node*8 + (lane>>3)] = s1; ad_o[node*8 + (lane>>3)] = s2; }
  } else {
    #pragma unroll
    for(int m=1;m<64;m<<=1){ s1 += __shfl_xor(s1,m); s2 += __shfl_xor(s2,m); }
    if(lane == 0){ as_o[node] = s1; ad_o[node] = s2; }
  }
}

// ---------------- aggregation: online segment softmax + weighted sum ----------------
// Wave per node. Coalesced chunk load of 64 edge indices, shuffle-broadcast,
// 4-edge-grouped online softmax for memory-level parallelism.
template<int HEADS, int DIM, bool DO_ELU, bool DO_LSM>
__global__ __launch_bounds__(256) void k_agg(const float* __restrict__ hprev, const int* __restrict__ rp,
                      const int* __restrict__ col,
                      const float* __restrict__ as_, const float* __restrict__ ad_,
                      const float* __restrict__ bias, float* __restrict__ out){
  int gid = blockIdx.x*256 + threadIdx.x;
  int node = gid >> 6, lane = gid & 63;
  if(node >= NN) return;
  constexpr int HD = HEADS*DIM;
  bool act = lane < HD;
  int hidx = act ? lane / DIM : 0;
  int beg = rp[node], end = rp[node+1];
  int deg = end - beg;
  float adn = ad_[node*HEADS + hidx];
  float m = -INFINITY, s = 0.f, acc = 0.f;

  for(int base = 0; base < deg; base += 64){
    int cnt = deg - base; if(cnt > 64) cnt = 64;
    int idx = 0;
    if(lane < cnt) idx = col[beg + base + lane];   // coalesced chunk load
    int j = 0;
    for(; j + 4 <= cnt; j += 4){
      int n0 = __shfl(idx, j);
      int n1 = __shfl(idx, j+1);
      int n2 = __shfl(idx, j+2);
      int n3 = __shfl(idx, j+3);
      // issue all gathers up front (8 outstanding loads)
      float e0 = as_[n0*HEADS + hidx];
      float e1 = as_[n1*HEADS + hidx];
      float e2 = as_[n2*HEADS + hidx];
      float e3 = as_[n3*HEADS + hidx];
      float h0 = act ? hprev[(size_t)n0*HD + lane] : 0.f;
      float h1 = act ? hprev[(size_t)n1*HD + lane] : 0.f;
      float h2 = act ? hprev[(size_t)n2*HD + lane] : 0.f;
      float h3 = act ? hprev[(size_t)n3*HD + lane] : 0.f;
      e0 += adn; e0 = (e0 > 0.f) ? e0 : 0.2f*e0;
      e1 += adn; e1 = (e1 > 0.f) ? e1 : 0.2f*e1;
      e2 += adn; e2 = (e2 > 0.f) ? e2 : 0.2f*e2;
      e3 += adn; e3 = (e3 > 0.f) ? e3 : 0.2f*e3;
      float gm = fmaxf(fmaxf(fmaxf(e0,e1), fmaxf(e2,e3)), m);
      float c  = __expf(m - gm);
      float p0 = __expf(e0 - gm);
      float p1 = __expf(e1 - gm);
      float p2 = __expf(e2 - gm);
      float p3 = __expf(e3 - gm);
      s   = s*c   + ((p0+p1) + (p2+p3));
      acc = acc*c + ((p0*h0 + p1*h1) + (p2*h2 + p3*h3));
      m = gm;
    }
    for(; j < cnt; j++){
      int srcn = __shfl(idx, j);
      float e = as_[srcn*HEADS + hidx] + adn;
      e = (e > 0.f) ? e : 0.2f*e;
      float mn = fmaxf(m, e);
      float c = __expf(m - mn);
      float p = __expf(e - mn);
      float hv = act ? hprev[(size_t)srcn*HD + lane] : 0.f;
      s = s*c + p;
      acc = acc*c + p*hv;
      m = mn;
    }
  }

  float o = acc/s + (act ? bias[lane] : 0.f);
  if(DO_ELU) o = (o > 0.f) ? o : expm1f(o);
  if(!DO_LSM){
    if(act) out[(size_t)node*HD + lane] = o;
  } else {
    float vmax = act ? o : -INFINITY;
    #pragma unroll
    for(int mm=1; mm<64; mm<<=1) vmax = fmaxf(vmax, __shfl_xor(vmax, mm));
    float ex = act ? expf(o - vmax) : 0.f;
    #pragma unroll
    for(int mm=1; mm<64; mm<<=1) ex += __shfl_xor(ex, mm);
    float res = o - vmax - logf(ex);
    if(act) out[(size_t)node*HD + lane] = res;
  }
}

// ---------------- launch ----------------
static inline size_t alignup(size_t x){ return (x + 255) & ~(size_t)255; }

extern "C" void kernel_launch(void* const* d_in, const int* in_sizes, int n_in,
                              void* d_out, int out_size, void* d_ws, size_t ws_size,
                              hipStream_t stream){
  const float* x      = (const float*)d_in[0];
  const int*   ei     = (const int*)d_in[1];
  const float* W1     = (const float*)d_in[2];
  const float* asrc1  = (const float*)d_in[3];
  const float* adst1  = (const float*)d_in[4];
  const float* b1     = (const float*)d_in[5];
  const float* W2     = (const float*)d_in[6];
  const float* asrc2  = (const float*)d_in[7];
  const float* adst2  = (const float*)d_in[8];
  const float* b2     = (const float*)d_in[9];
  const float* W3     = (const float*)d_in[10];
  const float* asrc3  = (const float*)d_in[11];
  const float* adst3  = (const float*)d_in[12];
  const float* b3     = (const float*)d_in[13];
  const int* src = ei;
  const int* dst = ei + EE;

  char* w = (char*)d_ws;
  int* cursor = (int*)w;              w += alignup((size_t)NN*4);
  int* rp     = (int*)w;              w += alignup((size_t)(NN+1)*4);
  int* bsum   = (int*)w;              w += alignup(512);
  int* col    = (int*)w;              w += alignup((size_t)ET*4);
  float* hA   = (float*)w;            w += alignup((size_t)NN*HDIM*4);
  float* hB   = (float*)w;            w += alignup((size_t)NN*HDIM*4);
  float* hC   = (float*)w;            w += alignup((size_t)NN*NCLS*4);
  float* asA  = (float*)w;            w += alignup((size_t)NN*8*4);
  float* adA  = (float*)w;            w += alignup((size_t)NN*8*4);

  dim3 blk(256);
  int gN   = (NN + 255)/256;
  int gE   = (EE + 255)/256;
  int gET  = (ET + 255)/256;
  int gWav = (NN*64 + 255)/256;   // wave per node
  int gGemm = (NN + 63)/64;

  // CSR
  k_init_cnt<<<gN, blk, 0, stream>>>(cursor);
  k_hist<<<gE, blk, 0, stream>>>(dst, cursor);
  k_scan1<<<98, blk, 0, stream>>>(cursor, rp, bsum);
  k_scan2<<<1, dim3(128), 0, stream>>>(bsum);
  k_add<<<gN, blk, 0, stream>>>(rp, cursor, bsum);
  k_scatter<<<gET, blk, 0, stream>>>(src, dst, cursor, col);

  // layer 1
  k_gemm<FIN, HDIM><<<gGemm, blk, 0, stream>>>(x, W1, hA, NN);
  k_att<8,8><<<gWav, blk, 0, stream>>>(hA, asrc1, adst1, asA, adA);
  k_agg<8,8,true,false><<<gWav, blk, 0, stream>>>(hA, rp, col, asA, adA, b1, hB);

  // layer 2
  k_gemm<HDIM, HDIM><<<gGemm, blk, 0, stream>>>(hB, W2, hA, NN);
  k_att<8,8><<<gWav, blk, 0, stream>>>(hA, asrc2, adst2, asA, adA);
  k_agg<8,8,true,false><<<gWav, blk, 0, stream>>>(hA, rp, col, asA, adA, b2, hB);

  // layer 3
  k_gemm<HDIM, NCLS><<<gGemm, blk, 0, stream>>>(hB, W3, hC, NN);
  k_att<1,NCLS><<<gWav, blk, 0, stream>>>(hC, asrc3, adst3, asA, adA);
  k_agg<1,NCLS,false,true><<<gWav, blk, 0, stream>>>(hC, rp, col, asA, adA, b3, (float*)d_out);
}

// Round 3
// 887.717 us; speedup vs baseline: 1.9605x; 1.3237x over previous
//
#include <hip/hip_runtime.h>
#include <math.h>

#define NN 100000
#define EE 3200000
#define ET 3300000   // EE + NN self loops
#define FIN 512
#define HDIM 64
#define NCLS 40

// bucket sort params
#define NBUK 512
#define NPB 196          // nodes per bucket; 511 buckets cover 100000
#define NBUK_USED 511
#define EPB 4096         // edges per block in bucket kernels
#define EPT 16           // edges per thread (256 threads)

// ---------------- CSR build via two-level bucket sort ----------------
__global__ void k_zeroB(int* bcnt){
  int t = blockIdx.x*256 + threadIdx.x;
  if(t < NBUK) bcnt[t] = 0;
}

__global__ __launch_bounds__(256) void k_bcount(const int* __restrict__ dst, int* __restrict__ bcnt){
  __shared__ int c[NBUK];
  int t = threadIdx.x;
  for(int i=t;i<NBUK;i+=256) c[i]=0;
  __syncthreads();
  int base = blockIdx.x*EPB + t;
  #pragma unroll
  for(int j=0;j<EPT;j++){
    int e = base + j*256;
    if(e < ET){
      int d = (e < EE) ? dst[e] : (e - EE);
      atomicAdd(&c[d/NPB], 1);
    }
  }
  __syncthreads();
  for(int i=t;i<NBUK;i+=256){ int v=c[i]; if(v) atomicAdd(&bcnt[i], v); }
}

__global__ void k_bscan(const int* __restrict__ bcnt, int* __restrict__ bbase, int* __restrict__ bcur){
  __shared__ int lds[NBUK];
  int t = threadIdx.x;                 // 512 threads
  int v = (t < NBUK_USED) ? bcnt[t] : 0;
  lds[t] = v;
  __syncthreads();
  for(int off=1; off<NBUK; off<<=1){
    int x = 0;
    if(t >= off) x = lds[t-off];
    __syncthreads();
    if(t >= off) lds[t] += x;
    __syncthreads();
  }
  int excl = lds[t] - v;
  bbase[t] = excl;
  bcur[t]  = excl;
  if(t == NBUK-1) bbase[NBUK] = ET;
}

__global__ __launch_bounds__(256) void k_bucket(const int* __restrict__ src, const int* __restrict__ dst,
                                                int* __restrict__ bcur, int* __restrict__ pbuf){
  __shared__ int lcnt[NBUK];
  __shared__ int lbase[NBUK];
  int t = threadIdx.x;
  for(int i=t;i<NBUK;i+=256) lcnt[i]=0;
  __syncthreads();
  int base = blockIdx.x*EPB + t;
  int bk[EPT], rk[EPT], pk[EPT];
  #pragma unroll
  for(int j=0;j<EPT;j++){
    int e = base + j*256;
    bk[j] = -1;
    if(e < ET){
      int s, d;
      if(e < EE){ s = src[e]; d = dst[e]; } else { s = e - EE; d = s; }
      int b = d / NPB;
      bk[j] = b;
      pk[j] = s | ((d - b*NPB) << 17);
      rk[j] = atomicAdd(&lcnt[b], 1);
    }
  }
  __syncthreads();
  for(int i=t;i<NBUK;i+=256){
    int v = lcnt[i];
    lbase[i] = v ? atomicAdd(&bcur[i], v) : 0;
  }
  __syncthreads();
  #pragma unroll
  for(int j=0;j<EPT;j++){
    if(bk[j] >= 0) pbuf[lbase[bk[j]] + rk[j]] = pk[j];
  }
}

__global__ __launch_bounds__(256) void k_bfinal(const int* __restrict__ bbase, const int* __restrict__ pbuf,
                                                int* __restrict__ rp, int* __restrict__ col){
  __shared__ int cnt[NPB];   // counts -> global cursors
  int b = blockIdx.x, t = threadIdx.x;
  int beg = bbase[b], end = bbase[b+1];
  for(int i=t;i<NPB;i+=256) cnt[i]=0;
  __syncthreads();
  for(int i=beg+t; i<end; i+=256){
    int dloc = pbuf[i] >> 17;
    atomicAdd(&cnt[dloc], 1);
  }
  __syncthreads();
  // exclusive scan over NPB elements by wave 0 (4 per lane)
  if(t < 64){
    int vals[4]; int sum = 0;
    #pragma unroll
    for(int j=0;j<4;j++){ int idx = t*4+j; int v = (idx<NPB)?cnt[idx]:0; vals[j]=v; sum+=v; }
    int incl = sum;
    #pragma unroll
    for(int off=1; off<64; off<<=1){
      int x = __shfl_up(incl, off);
      if(t >= off) incl += x;
    }
    int run = incl - sum;
    #pragma unroll
    for(int j=0;j<4;j++){
      int idx = t*4+j;
      if(idx < NPB){ int v = vals[j]; cnt[idx] = run; run += v; }
    }
  }
  __syncthreads();
  // write rp; convert cnt to global cursors
  int node0 = b*NPB;
  int nloc = NN - node0; if(nloc > NPB) nloc = NPB;
  for(int i=t;i<nloc;i+=256){
    int g = beg + cnt[i];
    rp[node0 + i] = g;
    cnt[i] = g;
  }
  if(b == 0 && t == 0) rp[NN] = ET;
  __syncthreads();
  for(int i=beg+t; i<end; i+=256){
    int v = pbuf[i];
    int s = v & 0x1FFFF;
    int dloc = v >> 17;
    int pos = atomicAdd(&cnt[dloc], 1);
    col[pos] = s;
  }
}

// ---------------- tiled f32 GEMM: Out[M x C] = A[M x K] @ W[K x C], C <= 64 ----------------
template<int K, int C>
__global__ __launch_bounds__(256) void k_gemm(const float* __restrict__ A, const float* __restrict__ W,
                                              float* __restrict__ Out, int M){
  __shared__ float As[64][68];
  __shared__ float Ws[64][68];
  int t = threadIdx.x;
  int row0 = blockIdx.x * 64;
  float acc[4][4] = {{0.f}};
  int tr = (t >> 4) * 4;
  int tc = (t & 15) * 4;
  int arow = t >> 2;
  int acol = (t & 3) * 16;

  for(int kc = 0; kc < K; kc += 64){
    int rg = row0 + arow; if(rg >= M) rg = M-1;
    #pragma unroll
    for(int j=0;j<4;j++){
      *(float4*)&As[arow][acol + 4*j] = *(const float4*)&A[(size_t)rg*K + kc + acol + 4*j];
    }
    #pragma unroll
    for(int j=0;j<16;j++){
      int c = acol + j;
      Ws[arow][c] = (c < C) ? W[(kc + arow)*C + c] : 0.f;
    }
    __syncthreads();
    for(int kk=0; kk<64; kk+=4){
      float4 A4[4], W4[4];
      #pragma unroll
      for(int i=0;i<4;i++) A4[i] = *(float4*)&As[tr+i][kk];
      #pragma unroll
      for(int q=0;q<4;q++) W4[q] = *(float4*)&Ws[kk+q][tc];
      #pragma unroll
      for(int i=0;i<4;i++){
        float4 a = A4[i];
        acc[i][0] += a.x*W4[0].x + a.y*W4[1].x + a.z*W4[2].x + a.w*W4[3].x;
        acc[i][1] += a.x*W4[0].y + a.y*W4[1].y + a.z*W4[2].y + a.w*W4[3].y;
        acc[i][2] += a.x*W4[0].z + a.y*W4[1].z + a.z*W4[2].z + a.w*W4[3].z;
        acc[i][3] += a.x*W4[0].w + a.y*W4[1].w + a.z*W4[2].w + a.w*W4[3].w;
      }
    }
    __syncthreads();
  }
  #pragma unroll
  for(int i=0;i<4;i++){
    int r = row0 + tr + i;
    if(r >= M) continue;
    #pragma unroll
    for(int j=0;j<4;j++){
      int c = tc + j;
      if(c < C) Out[(size_t)r*C + c] = acc[i][j];
    }
  }
}

// ---------------- per-node attention coefficients ----------------
template<int HEADS, int DIM>
__global__ void k_att(const float* __restrict__ h, const float* __restrict__ a_src,
                      const float* __restrict__ a_dst, float* __restrict__ as_o, float* __restrict__ ad_o){
  int gid = blockIdx.x*256 + threadIdx.x;
  int node = gid >> 6, lane = gid & 63;
  if(node >= NN) return;
  constexpr int HD = HEADS*DIM;
  float v = 0.f, asc = 0.f, adc = 0.f;
  if(lane < HD){ v = h[(size_t)node*HD + lane]; asc = a_src[lane]; adc = a_dst[lane]; }
  float s1 = v*asc, s2 = v*adc;
  if(HEADS == 8){
    #pragma unroll
    for(int m=1;m<8;m<<=1){ s1 += __shfl_xor(s1,m); s2 += __shfl_xor(s2,m); }
    if((lane & 7) == 0){ as_o[node*8 + (lane>>3)] = s1; ad_o[node*8 + (lane>>3)] = s2; }
  } else {
    #pragma unroll
    for(int m=1;m<64;m<<=1){ s1 += __shfl_xor(s1,m); s2 += __shfl_xor(s2,m); }
    if(lane == 0){ as_o[node] = s1; ad_o[node] = s2; }
  }
}

// ---------------- aggregation: online segment softmax + weighted sum ----------------
template<int HEADS, int DIM, bool DO_ELU, bool DO_LSM>
__global__ __launch_bounds__(256) void k_agg(const float* __restrict__ hprev, const int* __restrict__ rp,
                      const int* __restrict__ col,
                      const float* __restrict__ as_, const float* __restrict__ ad_,
                      const float* __restrict__ bias, float* __restrict__ out){
  int gid = blockIdx.x*256 + threadIdx.x;
  int node = gid >> 6, lane = gid & 63;
  if(node >= NN) return;
  constexpr int HD = HEADS*DIM;
  bool act = lane < HD;
  int hidx = act ? lane / DIM : 0;
  int beg = rp[node], end = rp[node+1];
  int deg = end - beg;
  float adn = ad_[node*HEADS + hidx];
  float m = -INFINITY, s = 0.f, acc = 0.f;

  for(int base = 0; base < deg; base += 64){
    int cnt = deg - base; if(cnt > 64) cnt = 64;
    int idx = 0;
    if(lane < cnt) idx = col[beg + base + lane];
    int j = 0;
    for(; j + 4 <= cnt; j += 4){
      int n0 = __shfl(idx, j);
      int n1 = __shfl(idx, j+1);
      int n2 = __shfl(idx, j+2);
      int n3 = __shfl(idx, j+3);
      float e0 = as_[n0*HEADS + hidx];
      float e1 = as_[n1*HEADS + hidx];
      float e2 = as_[n2*HEADS + hidx];
      float e3 = as_[n3*HEADS + hidx];
      float h0 = act ? hprev[(size_t)n0*HD + lane] : 0.f;
      float h1 = act ? hprev[(size_t)n1*HD + lane] : 0.f;
      float h2 = act ? hprev[(size_t)n2*HD + lane] : 0.f;
      float h3 = act ? hprev[(size_t)n3*HD + lane] : 0.f;
      e0 += adn; e0 = (e0 > 0.f) ? e0 : 0.2f*e0;
      e1 += adn; e1 = (e1 > 0.f) ? e1 : 0.2f*e1;
      e2 += adn; e2 = (e2 > 0.f) ? e2 : 0.2f*e2;
      e3 += adn; e3 = (e3 > 0.f) ? e3 : 0.2f*e3;
      float gm = fmaxf(fmaxf(fmaxf(e0,e1), fmaxf(e2,e3)), m);
      float c  = __expf(m - gm);
      float p0 = __expf(e0 - gm);
      float p1 = __expf(e1 - gm);
      float p2 = __expf(e2 - gm);
      float p3 = __expf(e3 - gm);
      s   = s*c   + ((p0+p1) + (p2+p3));
      acc = acc*c + ((p0*h0 + p1*h1) + (p2*h2 + p3*h3));
      m = gm;
    }
    for(; j < cnt; j++){
      int srcn = __shfl(idx, j);
      float e = as_[srcn*HEADS + hidx] + adn;
      e = (e > 0.f) ? e : 0.2f*e;
      float mn = fmaxf(m, e);
      float c = __expf(m - mn);
      float p = __expf(e - mn);
      float hv = act ? hprev[(size_t)srcn*HD + lane] : 0.f;
      s = s*c + p;
      acc = acc*c + p*hv;
      m = mn;
    }
  }

  float o = acc/s + (act ? bias[lane] : 0.f);
  if(DO_ELU) o = (o > 0.f) ? o : expm1f(o);
  if(!DO_LSM){
    if(act) out[(size_t)node*HD + lane] = o;
  } else {
    float vmax = act ? o : -INFINITY;
    #pragma unroll
    for(int mm=1; mm<64; mm<<=1) vmax = fmaxf(vmax, __shfl_xor(vmax, mm));
    float ex = act ? expf(o - vmax) : 0.f;
    #pragma unroll
    for(int mm=1; mm<64; mm<<=1) ex += __shfl_xor(ex, mm);
    float res = o - vmax - logf(ex);
    if(act) out[(size_t)node*HD + lane] = res;
  }
}

// ---------------- launch ----------------
static inline size_t alignup(size_t x){ return (x + 255) & ~(size_t)255; }

extern "C" void kernel_launch(void* const* d_in, const int* in_sizes, int n_in,
                              void* d_out, int out_size, void* d_ws, size_t ws_size,
                              hipStream_t stream){
  const float* x      = (const float*)d_in[0];
  const int*   ei     = (const int*)d_in[1];
  const float* W1     = (const float*)d_in[2];
  const float* asrc1  = (const float*)d_in[3];
  const float* adst1  = (const float*)d_in[4];
  const float* b1     = (const float*)d_in[5];
  const float* W2     = (const float*)d_in[6];
  const float* asrc2  = (const float*)d_in[7];
  const float* adst2  = (const float*)d_in[8];
  const float* b2     = (const float*)d_in[9];
  const float* W3     = (const float*)d_in[10];
  const float* asrc3  = (const float*)d_in[11];
  const float* adst3  = (const float*)d_in[12];
  const float* b3     = (const float*)d_in[13];
  const int* src = ei;
  const int* dst = ei + EE;

  char* w = (char*)d_ws;
  int* rp     = (int*)w;              w += alignup((size_t)(NN+1)*4);
  int* bcnt   = (int*)w;              w += alignup((size_t)NBUK*4);
  int* bbase  = (int*)w;              w += alignup((size_t)(NBUK+1)*4);
  int* bcur   = (int*)w;              w += alignup((size_t)NBUK*4);
  int* col    = (int*)w;              w += alignup((size_t)ET*4);
  float* hA   = (float*)w;            w += alignup((size_t)NN*HDIM*4);
  float* hB   = (float*)w;            w += alignup((size_t)NN*HDIM*4);
  float* hC   = (float*)w;            w += alignup((size_t)NN*NCLS*4);  // also pbuf (ET ints <= NN*NCLS)
  float* asA  = (float*)w;            w += alignup((size_t)NN*8*4);
  float* adA  = (float*)w;            w += alignup((size_t)NN*8*4);
  int* pbuf   = (int*)hC;

  dim3 blk(256);
  int gWav  = (NN*64 + 255)/256;   // wave per node
  int gGemm = (NN + 63)/64;
  int gBuk  = (ET + EPB - 1)/EPB;

  // CSR build (bucket sort)
  k_zeroB<<<2, blk, 0, stream>>>(bcnt);
  k_bcount<<<gBuk, blk, 0, stream>>>(dst, bcnt);
  k_bscan<<<1, dim3(NBUK), 0, stream>>>(bcnt, bbase, bcur);
  k_bucket<<<gBuk, blk, 0, stream>>>(src, dst, bcur, pbuf);
  k_bfinal<<<NBUK_USED, blk, 0, stream>>>(bbase, pbuf, rp, col);

  // layer 1
  k_gemm<FIN, HDIM><<<gGemm, blk, 0, stream>>>(x, W1, hA, NN);
  k_att<8,8><<<gWav, blk, 0, stream>>>(hA, asrc1, adst1, asA, adA);
  k_agg<8,8,true,false><<<gWav, blk, 0, stream>>>(hA, rp, col, asA, adA, b1, hB);

  // layer 2
  k_gemm<HDIM, HDIM><<<gGemm, blk, 0, stream>>>(hB, W2, hA, NN);
  k_att<8,8><<<gWav, blk, 0, stream>>>(hA, asrc2, adst2, asA, adA);
  k_agg<8,8,true,false><<<gWav, blk, 0, stream>>>(hA, rp, col, asA, adA, b2, hB);

  // layer 3
  k_gemm<HDIM, NCLS><<<gGemm, blk, 0, stream>>>(hB, W3, hC, NN);
  k_att<1,NCLS><<<gWav, blk, 0, stream>>>(hC, asrc3, adst3, asA, adA);
  k_agg<1,NCLS,false,true><<<gWav, blk, 0, stream>>>(hC, rp, col, asA, adA, b3, (float*)d_out);
}

// Round 4
// 733.621 us; speedup vs baseline: 2.3723x; 1.2100x over previous
//
#include <hip/hip_runtime.h>
#include <math.h>

#define NN 100000
#define EE 3200000
#define ET 3300000   // EE + NN self loops
#define FIN 512
#define HDIM 64
#define NCLS 40

// bucket sort params
#define NBUK 512
#define NPB 196          // nodes per bucket; 511 buckets cover 100000
#define NBUK_USED 511
#define EPB 4096         // edges per block in bucket kernels
#define EPT 16           // edges per thread (256 threads)

typedef __attribute__((ext_vector_type(8))) short frag_ab;
typedef __attribute__((ext_vector_type(4))) float frag_cd;

__device__ inline unsigned short f2bf(float f){
  union { float f; unsigned int u; } x; x.f = f;
  unsigned int u = x.u;
  unsigned int r = u + 0x7FFF + ((u >> 16) & 1);
  return (unsigned short)(r >> 16);
}

// ---------------- CSR build via two-level bucket sort ----------------
__global__ void k_zeroB(int* bcnt){
  int t = blockIdx.x*256 + threadIdx.x;
  if(t < NBUK) bcnt[t] = 0;
}

__global__ __launch_bounds__(256) void k_bcount(const int* __restrict__ dst, int* __restrict__ bcnt){
  __shared__ int c[NBUK];
  int t = threadIdx.x;
  for(int i=t;i<NBUK;i+=256) c[i]=0;
  __syncthreads();
  int base = blockIdx.x*EPB + t;
  #pragma unroll
  for(int j=0;j<EPT;j++){
    int e = base + j*256;
    if(e < ET){
      int d = (e < EE) ? dst[e] : (e - EE);
      atomicAdd(&c[d/NPB], 1);
    }
  }
  __syncthreads();
  for(int i=t;i<NBUK;i+=256){ int v=c[i]; if(v) atomicAdd(&bcnt[i], v); }
}

__global__ void k_bscan(const int* __restrict__ bcnt, int* __restrict__ bbase, int* __restrict__ bcur){
  __shared__ int lds[NBUK];
  int t = threadIdx.x;                 // 512 threads
  int v = (t < NBUK_USED) ? bcnt[t] : 0;
  lds[t] = v;
  __syncthreads();
  for(int off=1; off<NBUK; off<<=1){
    int x = 0;
    if(t >= off) x = lds[t-off];
    __syncthreads();
    if(t >= off) lds[t] += x;
    __syncthreads();
  }
  int excl = lds[t] - v;
  bbase[t] = excl;
  bcur[t]  = excl;
  if(t == NBUK-1) bbase[NBUK] = ET;
}

__global__ __launch_bounds__(256) void k_bucket(const int* __restrict__ src, const int* __restrict__ dst,
                                                int* __restrict__ bcur, int* __restrict__ pbuf){
  __shared__ int lcnt[NBUK];
  __shared__ int lbase[NBUK];
  int t = threadIdx.x;
  for(int i=t;i<NBUK;i+=256) lcnt[i]=0;
  __syncthreads();
  int base = blockIdx.x*EPB + t;
  int bk[EPT], rk[EPT], pk[EPT];
  #pragma unroll
  for(int j=0;j<EPT;j++){
    int e = base + j*256;
    bk[j] = -1;
    if(e < ET){
      int s, d;
      if(e < EE){ s = src[e]; d = dst[e]; } else { s = e - EE; d = s; }
      int b = d / NPB;
      bk[j] = b;
      pk[j] = s | ((d - b*NPB) << 17);
      rk[j] = atomicAdd(&lcnt[b], 1);
    }
  }
  __syncthreads();
  for(int i=t;i<NBUK;i+=256){
    int v = lcnt[i];
    lbase[i] = v ? atomicAdd(&bcur[i], v) : 0;
  }
  __syncthreads();
  #pragma unroll
  for(int j=0;j<EPT;j++){
    if(bk[j] >= 0) pbuf[lbase[bk[j]] + rk[j]] = pk[j];
  }
}

__global__ __launch_bounds__(256) void k_bfinal(const int* __restrict__ bbase, const int* __restrict__ pbuf,
                                                int* __restrict__ rp, int* __restrict__ col){
  __shared__ int cnt[NPB];   // counts -> global cursors
  int b = blockIdx.x, t = threadIdx.x;
  int beg = bbase[b], end = bbase[b+1];
  for(int i=t;i<NPB;i+=256) cnt[i]=0;
  __syncthreads();
  for(int i=beg+t; i<end; i+=256){
    int dloc = pbuf[i] >> 17;
    atomicAdd(&cnt[dloc], 1);
  }
  __syncthreads();
  if(t < 64){
    int vals[4]; int sum = 0;
    #pragma unroll
    for(int j=0;j<4;j++){ int idx = t*4+j; int v = (idx<NPB)?cnt[idx]:0; vals[j]=v; sum+=v; }
    int incl = sum;
    #pragma unroll
    for(int off=1; off<64; off<<=1){
      int x = __shfl_up(incl, off);
      if(t >= off) incl += x;
    }
    int run = incl - sum;
    #pragma unroll
    for(int j=0;j<4;j++){
      int idx = t*4+j;
      if(idx < NPB){ int v = vals[j]; cnt[idx] = run; run += v; }
    }
  }
  __syncthreads();
  int node0 = b*NPB;
  int nloc = NN - node0; if(nloc > NPB) nloc = NPB;
  for(int i=t;i<nloc;i+=256){
    int g = beg + cnt[i];
    rp[node0 + i] = g;
    cnt[i] = g;
  }
  if(b == 0 && t == 0) rp[NN] = ET;
  __syncthreads();
  for(int i=beg+t; i<end; i+=256){
    int v = pbuf[i];
    int s = v & 0x1FFFF;
    int dloc = v >> 17;
    int pos = atomicAdd(&cnt[dloc], 1);
    col[pos] = s;
  }
}

// ---------------- W1 -> bf16 transposed [64][512] ----------------
__global__ void k_cvtW(const float* __restrict__ W, unsigned short* __restrict__ Wt){
  int i = blockIdx.x*256 + threadIdx.x;   // 32768 total
  if(i >= FIN*HDIM) return;
  int k = i >> 6, n = i & 63;
  Wt[n*FIN + k] = f2bf(W[i]);
}

// ---------------- GEMM1: bf16 MFMA, Out[M x 64] = A[M x 512] @ W ----------------
#define BM 128
#define BK 32
#define LSTR 40   // bf16 elems per LDS row (80 B, odd word-cycle -> <=2-way)
__global__ __launch_bounds__(256) void k_gemm1(const float* __restrict__ A, const unsigned short* __restrict__ Wt,
                                               float* __restrict__ Out, int M){
  __shared__ __attribute__((aligned(16))) unsigned short Al[2][BM*LSTR];
  __shared__ __attribute__((aligned(16))) unsigned short Bl[2][64*LSTR];
  int t = threadIdx.x;
  int w = t >> 6, l = t & 63;
  int row0 = blockIdx.x * BM;

  int srow = t >> 1;          // 0..127 A-stage row
  int shalf = t & 1;          // 16-float col offset
  int bn = t >> 2;            // 0..63 B-stage col
  int bseg = t & 3;           // 8-bf16 segment

  int fr = l & 15, kg = l >> 4;

  frag_cd acc[2][4];
  #pragma unroll
  for(int i=0;i<2;i++)
    #pragma unroll
    for(int j=0;j<4;j++) acc[i][j] = (frag_cd){0.f,0.f,0.f,0.f};

  int rg = row0 + srow; if(rg >= M) rg = M-1;
  const float* aprow = &A[(size_t)rg*FIN + shalf*16];

  // ---- stage lambda (macro-style) ----
  #define STAGE(buf, kc) do { \
    const float* ap = aprow + (kc); \
    float4 v0 = *(const float4*)(ap); \
    float4 v1 = *(const float4*)(ap+4); \
    float4 v2 = *(const float4*)(ap+8); \
    float4 v3 = *(const float4*)(ap+12); \
    uint4 pa, pb; \
    pa.x = f2bf(v0.x) | ((unsigned)f2bf(v0.y)<<16); \
    pa.y = f2bf(v0.z) | ((unsigned)f2bf(v0.w)<<16); \
    pa.z = f2bf(v1.x) | ((unsigned)f2bf(v1.y)<<16); \
    pa.w = f2bf(v1.z) | ((unsigned)f2bf(v1.w)<<16); \
    pb.x = f2bf(v2.x) | ((unsigned)f2bf(v2.y)<<16); \
    pb.y = f2bf(v2.z) | ((unsigned)f2bf(v2.w)<<16); \
    pb.z = f2bf(v3.x) | ((unsigned)f2bf(v3.y)<<16); \
    pb.w = f2bf(v3.z) | ((unsigned)f2bf(v3.w)<<16); \
    *(uint4*)&Al[buf][srow*LSTR + shalf*16] = pa; \
    *(uint4*)&Al[buf][srow*LSTR + shalf*16 + 8] = pb; \
    *(uint4*)&Bl[buf][bn*LSTR + bseg*8] = *(const uint4*)&Wt[bn*FIN + (kc) + bseg*8]; \
  } while(0)

  STAGE(0, 0);
  __syncthreads();

  #pragma unroll 1
  for(int step = 0; step < FIN/BK; ++step){
    int buf = step & 1;
    if(step + 1 < FIN/BK) STAGE(buf^1, (step+1)*BK);
    frag_ab af[2], bf[4];
    #pragma unroll
    for(int i=0;i<2;i++) af[i] = *(const frag_ab*)&Al[buf][(w*32 + i*16 + fr)*LSTR + kg*8];
    #pragma unroll
    for(int j=0;j<4;j++) bf[j] = *(const frag_ab*)&Bl[buf][(j*16 + fr)*LSTR + kg*8];
    #pragma unroll
    for(int i=0;i<2;i++)
      #pragma unroll
      for(int j=0;j<4;j++)
        acc[i][j] = __builtin_amdgcn_mfma_f32_16x16x32_bf16(af[i], bf[j], acc[i][j], 0, 0, 0);
    __syncthreads();
  }

  // epilogue: C/D layout col = l&15, row = 4*(l>>4) + reg
  #pragma unroll
  for(int i=0;i<2;i++){
    int crow = row0 + w*32 + i*16 + kg*4;
    #pragma unroll
    for(int j=0;j<4;j++){
      int ccol = j*16 + fr;
      #pragma unroll
      for(int r=0;r<4;r++){
        if(crow + r < M) Out[(size_t)(crow+r)*HDIM + ccol] = acc[i][j][r];
      }
    }
  }
  #undef STAGE
}

// ---------------- tiled f32 GEMM (layers 2,3): Out[M x C] = A[M x K] @ W[K x C] ----------------
template<int K, int C>
__global__ __launch_bounds__(256) void k_gemm(const float* __restrict__ A, const float* __restrict__ W,
                                              float* __restrict__ Out, int M){
  __shared__ float As[64][68];
  __shared__ float Ws[64][68];
  int t = threadIdx.x;
  int row0 = blockIdx.x * 64;
  float acc[4][4] = {{0.f}};
  int tr = (t >> 4) * 4;
  int tc = (t & 15) * 4;
  int arow = t >> 2;
  int acol = (t & 3) * 16;

  for(int kc = 0; kc < K; kc += 64){
    int rg = row0 + arow; if(rg >= M) rg = M-1;
    #pragma unroll
    for(int j=0;j<4;j++){
      *(float4*)&As[arow][acol + 4*j] = *(const float4*)&A[(size_t)rg*K + kc + acol + 4*j];
    }
    #pragma unroll
    for(int j=0;j<16;j++){
      int c = acol + j;
      Ws[arow][c] = (c < C) ? W[(kc + arow)*C + c] : 0.f;
    }
    __syncthreads();
    for(int kk=0; kk<64; kk+=4){
      float4 A4[4], W4[4];
      #pragma unroll
      for(int i=0;i<4;i++) A4[i] = *(float4*)&As[tr+i][kk];
      #pragma unroll
      for(int q=0;q<4;q++) W4[q] = *(float4*)&Ws[kk+q][tc];
      #pragma unroll
      for(int i=0;i<4;i++){
        float4 a = A4[i];
        acc[i][0] += a.x*W4[0].x + a.y*W4[1].x + a.z*W4[2].x + a.w*W4[3].x;
        acc[i][1] += a.x*W4[0].y + a.y*W4[1].y + a.z*W4[2].y + a.w*W4[3].y;
        acc[i][2] += a.x*W4[0].z + a.y*W4[1].z + a.z*W4[2].z + a.w*W4[3].z;
        acc[i][3] += a.x*W4[0].w + a.y*W4[1].w + a.z*W4[2].w + a.w*W4[3].w;
      }
    }
    __syncthreads();
  }
  #pragma unroll
  for(int i=0;i<4;i++){
    int r = row0 + tr + i;
    if(r >= M) continue;
    #pragma unroll
    for(int j=0;j<4;j++){
      int c = tc + j;
      if(c < C) Out[(size_t)r*C + c] = acc[i][j];
    }
  }
}

// ---------------- per-node attention coefficients ----------------
template<int HEADS, int DIM>
__global__ void k_att(const float* __restrict__ h, const float* __restrict__ a_src,
                      const float* __restrict__ a_dst, float* __restrict__ as_o, float* __restrict__ ad_o){
  int gid = blockIdx.x*256 + threadIdx.x;
  int node = gid >> 6, lane = gid & 63;
  if(node >= NN) return;
  constexpr int HD = HEADS*DIM;
  float v = 0.f, asc = 0.f, adc = 0.f;
  if(lane < HD){ v = h[(size_t)node*HD + lane]; asc = a_src[lane]; adc = a_dst[lane]; }
  float s1 = v*asc, s2 = v*adc;
  if(HEADS == 8){
    #pragma unroll
    for(int m=1;m<8;m<<=1){ s1 += __shfl_xor(s1,m); s2 += __shfl_xor(s2,m); }
    if((lane & 7) == 0){ as_o[node*8 + (lane>>3)] = s1; ad_o[node*8 + (lane>>3)] = s2; }
  } else {
    #pragma unroll
    for(int m=1;m<64;m<<=1){ s1 += __shfl_xor(s1,m); s2 += __shfl_xor(s2,m); }
    if(lane == 0){ as_o[node] = s1; ad_o[node] = s2; }
  }
}

// ---------------- aggregation: online segment softmax + weighted sum ----------------
template<int HEADS, int DIM, bool DO_ELU, bool DO_LSM>
__global__ __launch_bounds__(256) void k_agg(const float* __restrict__ hprev, const int* __restrict__ rp,
                      const int* __restrict__ col,
                      const float* __restrict__ as_, const float* __restrict__ ad_,
                      const float* __restrict__ bias, float* __restrict__ out){
  int gid = blockIdx.x*256 + threadIdx.x;
  int node = gid >> 6, lane = gid & 63;
  if(node >= NN) return;
  constexpr int HD = HEADS*DIM;
  bool act = lane < HD;
  int hidx = act ? lane / DIM : 0;
  int beg = rp[node], end = rp[node+1];
  int deg = end - beg;
  float adn = ad_[node*HEADS + hidx];
  float m = -INFINITY, s = 0.f, acc = 0.f;

  for(int base = 0; base < deg; base += 64){
    int cnt = deg - base; if(cnt > 64) cnt = 64;
    int idx = 0;
    if(lane < cnt) idx = col[beg + base + lane];
    int j = 0;
    for(; j + 4 <= cnt; j += 4){
      int n0 = __shfl(idx, j);
      int n1 = __shfl(idx, j+1);
      int n2 = __shfl(idx, j+2);
      int n3 = __shfl(idx, j+3);
      float e0 = as_[n0*HEADS + hidx];
      float e1 = as_[n1*HEADS + hidx];
      float e2 = as_[n2*HEADS + hidx];
      float e3 = as_[n3*HEADS + hidx];
      float h0 = act ? hprev[(size_t)n0*HD + lane] : 0.f;
      float h1 = act ? hprev[(size_t)n1*HD + lane] : 0.f;
      float h2 = act ? hprev[(size_t)n2*HD + lane] : 0.f;
      float h3 = act ? hprev[(size_t)n3*HD + lane] : 0.f;
      e0 += adn; e0 = (e0 > 0.f) ? e0 : 0.2f*e0;
      e1 += adn; e1 = (e1 > 0.f) ? e1 : 0.2f*e1;
      e2 += adn; e2 = (e2 > 0.f) ? e2 : 0.2f*e2;
      e3 += adn; e3 = (e3 > 0.f) ? e3 : 0.2f*e3;
      float gm = fmaxf(fmaxf(fmaxf(e0,e1), fmaxf(e2,e3)), m);
      float c  = __expf(m - gm);
      float p0 = __expf(e0 - gm);
      float p1 = __expf(e1 - gm);
      float p2 = __expf(e2 - gm);
      float p3 = __expf(e3 - gm);
      s   = s*c   + ((p0+p1) + (p2+p3));
      acc = acc*c + ((p0*h0 + p1*h1) + (p2*h2 + p3*h3));
      m = gm;
    }
    for(; j < cnt; j++){
      int srcn = __shfl(idx, j);
      float e = as_[srcn*HEADS + hidx] + adn;
      e = (e > 0.f) ? e : 0.2f*e;
      float mn = fmaxf(m, e);
      float c = __expf(m - mn);
      float p = __expf(e - mn);
      float hv = act ? hprev[(size_t)srcn*HD + lane] : 0.f;
      s = s*c + p;
      acc = acc*c + p*hv;
      m = mn;
    }
  }

  float o = acc/s + (act ? bias[lane] : 0.f);
  if(DO_ELU) o = (o > 0.f) ? o : expm1f(o);
  if(!DO_LSM){
    if(act) out[(size_t)node*HD + lane] = o;
  } else {
    float vmax = act ? o : -INFINITY;
    #pragma unroll
    for(int mm=1; mm<64; mm<<=1) vmax = fmaxf(vmax, __shfl_xor(vmax, mm));
    float ex = act ? expf(o - vmax) : 0.f;
    #pragma unroll
    for(int mm=1; mm<64; mm<<=1) ex += __shfl_xor(ex, mm);
    float res = o - vmax - logf(ex);
    if(act) out[(size_t)node*HD + lane] = res;
  }
}

// ---------------- launch ----------------
static inline size_t alignup(size_t x){ return (x + 255) & ~(size_t)255; }

extern "C" void kernel_launch(void* const* d_in, const int* in_sizes, int n_in,
                              void* d_out, int out_size, void* d_ws, size_t ws_size,
                              hipStream_t stream){
  const float* x      = (const float*)d_in[0];
  const int*   ei     = (const int*)d_in[1];
  const float* W1     = (const float*)d_in[2];
  const float* asrc1  = (const float*)d_in[3];
  const float* adst1  = (const float*)d_in[4];
  const float* b1     = (const float*)d_in[5];
  const float* W2     = (const float*)d_in[6];
  const float* asrc2  = (const float*)d_in[7];
  const float* adst2  = (const float*)d_in[8];
  const float* b2     = (const float*)d_in[9];
  const float* W3     = (const float*)d_in[10];
  const float* asrc3  = (const float*)d_in[11];
  const float* adst3  = (const float*)d_in[12];
  const float* b3     = (const float*)d_in[13];
  const int* src = ei;
  const int* dst = ei + EE;

  char* w = (char*)d_ws;
  int* rp     = (int*)w;              w += alignup((size_t)(NN+1)*4);
  int* bcnt   = (int*)w;              w += alignup((size_t)NBUK*4);
  int* bbase  = (int*)w;              w += alignup((size_t)(NBUK+1)*4);
  int* bcur   = (int*)w;              w += alignup((size_t)NBUK*4);
  unsigned short* Wt = (unsigned short*)w; w += alignup((size_t)FIN*HDIM*2);
  int* col    = (int*)w;              w += alignup((size_t)ET*4);
  float* hA   = (float*)w;            w += alignup((size_t)NN*HDIM*4);
  float* hB   = (float*)w;            w += alignup((size_t)NN*HDIM*4);
  float* hC   = (float*)w;            w += alignup((size_t)NN*NCLS*4);  // also pbuf
  float* asA  = (float*)w;            w += alignup((size_t)NN*8*4);
  float* adA  = (float*)w;            w += alignup((size_t)NN*8*4);
  int* pbuf   = (int*)hC;

  dim3 blk(256);
  int gWav  = (NN*64 + 255)/256;
  int gGemm = (NN + 63)/64;
  int gG1   = (NN + BM - 1)/BM;
  int gBuk  = (ET + EPB - 1)/EPB;

  // CSR build (bucket sort)
  k_zeroB<<<2, blk, 0, stream>>>(bcnt);
  k_bcount<<<gBuk, blk, 0, stream>>>(dst, bcnt);
  k_bscan<<<1, dim3(NBUK), 0, stream>>>(bcnt, bbase, bcur);
  k_bucket<<<gBuk, blk, 0, stream>>>(src, dst, bcur, pbuf);
  k_bfinal<<<NBUK_USED, blk, 0, stream>>>(bbase, pbuf, rp, col);

  // layer 1 (bf16 MFMA GEMM)
  k_cvtW<<<(FIN*HDIM + 255)/256, blk, 0, stream>>>(W1, Wt);
  k_gemm1<<<gG1, blk, 0, stream>>>(x, Wt, hA, NN);
  k_att<8,8><<<gWav, blk, 0, stream>>>(hA, asrc1, adst1, asA, adA);
  k_agg<8,8,true,false><<<gWav, blk, 0, stream>>>(hA, rp, col, asA, adA, b1, hB);

  // layer 2
  k_gemm<HDIM, HDIM><<<gGemm, blk, 0, stream>>>(hB, W2, hA, NN);
  k_att<8,8><<<gWav, blk, 0, stream>>>(hA, asrc2, adst2, asA, adA);
  k_agg<8,8,true,false><<<gWav, blk, 0, stream>>>(hA, rp, col, asA, adA, b2, hB);

  // layer 3
  k_gemm<HDIM, NCLS><<<gGemm, blk, 0, stream>>>(hB, W3, hC, NN);
  k_att<1,NCLS><<<gWav, blk, 0, stream>>>(hC, asrc3, adst3, asA, adA);
  k_agg<1,NCLS,false,true><<<gWav, blk, 0, stream>>>(hC, rp, col, asA, adA, b3, (float*)d_out);
}

// Round 5
// 602.447 us; speedup vs baseline: 2.8888x; 1.2177x over previous
//
#include <hip/hip_runtime.h>
#include <math.h>

#define NN 100000
#define EE 3200000
#define ET 3300000   // EE + NN self loops
#define FIN 512
#define HDIM 64
#define NCLS 40

// bucket sort params
#define NBUK 512
#define NPB 196
#define NBUK_USED 511
#define EPB 4096
#define EPT 16

typedef __attribute__((ext_vector_type(8))) short frag_ab;
typedef __attribute__((ext_vector_type(4))) float frag_cd;

__device__ inline unsigned short f2bf(float f){
  union { float f; unsigned int u; } x; x.f = f;
  unsigned int u = x.u;
  unsigned int r = u + 0x7FFF + ((u >> 16) & 1);
  return (unsigned short)(r >> 16);
}
__device__ inline float bf2f(unsigned short u){
  union { unsigned int u; float f; } x; x.u = ((unsigned int)u) << 16;
  return x.f;
}

// ---------------- CSR build via two-level bucket sort ----------------
__global__ void k_zeroB(int* bcnt){
  int t = blockIdx.x*256 + threadIdx.x;
  if(t < NBUK) bcnt[t] = 0;
}

__global__ __launch_bounds__(256) void k_bcount(const int* __restrict__ dst, int* __restrict__ bcnt){
  __shared__ int c[NBUK];
  int t = threadIdx.x;
  for(int i=t;i<NBUK;i+=256) c[i]=0;
  __syncthreads();
  int base = blockIdx.x*EPB + t;
  #pragma unroll
  for(int j=0;j<EPT;j++){
    int e = base + j*256;
    if(e < ET){
      int d = (e < EE) ? dst[e] : (e - EE);
      atomicAdd(&c[d/NPB], 1);
    }
  }
  __syncthreads();
  for(int i=t;i<NBUK;i+=256){ int v=c[i]; if(v) atomicAdd(&bcnt[i], v); }
}

__global__ void k_bscan(const int* __restrict__ bcnt, int* __restrict__ bbase, int* __restrict__ bcur){
  __shared__ int lds[NBUK];
  int t = threadIdx.x;                 // 512 threads
  int v = (t < NBUK_USED) ? bcnt[t] : 0;
  lds[t] = v;
  __syncthreads();
  for(int off=1; off<NBUK; off<<=1){
    int x = 0;
    if(t >= off) x = lds[t-off];
    __syncthreads();
    if(t >= off) lds[t] += x;
    __syncthreads();
  }
  int excl = lds[t] - v;
  bbase[t] = excl;
  bcur[t]  = excl;
  if(t == NBUK-1) bbase[NBUK] = ET;
}

__global__ __launch_bounds__(256) void k_bucket(const int* __restrict__ src, const int* __restrict__ dst,
                                                int* __restrict__ bcur, int* __restrict__ pbuf){
  __shared__ int lcnt[NBUK];
  __shared__ int lbase[NBUK];
  int t = threadIdx.x;
  for(int i=t;i<NBUK;i+=256) lcnt[i]=0;
  __syncthreads();
  int base = blockIdx.x*EPB + t;
  int bk[EPT], rk[EPT], pk[EPT];
  #pragma unroll
  for(int j=0;j<EPT;j++){
    int e = base + j*256;
    bk[j] = -1;
    if(e < ET){
      int s, d;
      if(e < EE){ s = src[e]; d = dst[e]; } else { s = e - EE; d = s; }
      int b = d / NPB;
      bk[j] = b;
      pk[j] = s | ((d - b*NPB) << 17);
      rk[j] = atomicAdd(&lcnt[b], 1);
    }
  }
  __syncthreads();
  for(int i=t;i<NBUK;i+=256){
    int v = lcnt[i];
    lbase[i] = v ? atomicAdd(&bcur[i], v) : 0;
  }
  __syncthreads();
  #pragma unroll
  for(int j=0;j<EPT;j++){
    if(bk[j] >= 0) pbuf[lbase[bk[j]] + rk[j]] = pk[j];
  }
}

__global__ __launch_bounds__(256) void k_bfinal(const int* __restrict__ bbase, const int* __restrict__ pbuf,
                                                int* __restrict__ rp, int* __restrict__ col){
  __shared__ int cnt[NPB];
  int b = blockIdx.x, t = threadIdx.x;
  int beg = bbase[b], end = bbase[b+1];
  for(int i=t;i<NPB;i+=256) cnt[i]=0;
  __syncthreads();
  for(int i=beg+t; i<end; i+=256){
    int dloc = pbuf[i] >> 17;
    atomicAdd(&cnt[dloc], 1);
  }
  __syncthreads();
  if(t < 64){
    int vals[4]; int sum = 0;
    #pragma unroll
    for(int j=0;j<4;j++){ int idx = t*4+j; int v = (idx<NPB)?cnt[idx]:0; vals[j]=v; sum+=v; }
    int incl = sum;
    #pragma unroll
    for(int off=1; off<64; off<<=1){
      int x = __shfl_up(incl, off);
      if(t >= off) incl += x;
    }
    int run = incl - sum;
    #pragma unroll
    for(int j=0;j<4;j++){
      int idx = t*4+j;
      if(idx < NPB){ int v = vals[j]; cnt[idx] = run; run += v; }
    }
  }
  __syncthreads();
  int node0 = b*NPB;
  int nloc = NN - node0; if(nloc > NPB) nloc = NPB;
  for(int i=t;i<nloc;i+=256){
    int g = beg + cnt[i];
    rp[node0 + i] = g;
    cnt[i] = g;
  }
  if(b == 0 && t == 0) rp[NN] = ET;
  __syncthreads();
  for(int i=beg+t; i<end; i+=256){
    int v = pbuf[i];
    int s = v & 0x1FFFF;
    int dloc = v >> 17;
    int pos = atomicAdd(&cnt[dloc], 1);
    col[pos] = s;
  }
}

// ---------------- W1 -> bf16 transposed [64][512] ----------------
__global__ void k_cvtW(const float* __restrict__ W, unsigned short* __restrict__ Wt){
  int i = blockIdx.x*256 + threadIdx.x;
  if(i >= FIN*HDIM) return;
  int k = i >> 6, n = i & 63;
  Wt[n*FIN + k] = f2bf(W[i]);
}

// ---------------- GEMM1: bf16 MFMA, Outbf[M x 64] = A[M x 512] @ W ----------------
#define BM 128
#define BK 32
#define LSTR 40
__global__ __launch_bounds__(256) void k_gemm1(const float* __restrict__ A, const unsigned short* __restrict__ Wt,
                                               unsigned short* __restrict__ Out, int M){
  __shared__ __attribute__((aligned(16))) unsigned short Al[2][BM*LSTR];
  __shared__ __attribute__((aligned(16))) unsigned short Bl[2][64*LSTR];
  int t = threadIdx.x;
  int w = t >> 6, l = t & 63;
  int row0 = blockIdx.x * BM;

  int srow = t >> 1;
  int shalf = t & 1;
  int bn = t >> 2;
  int bseg = t & 3;

  int fr = l & 15, kg = l >> 4;

  frag_cd acc[2][4];
  #pragma unroll
  for(int i=0;i<2;i++)
    #pragma unroll
    for(int j=0;j<4;j++) acc[i][j] = (frag_cd){0.f,0.f,0.f,0.f};

  int rg = row0 + srow; if(rg >= M) rg = M-1;
  const float* aprow = &A[(size_t)rg*FIN + shalf*16];

  #define STAGE(buf, kc) do { \
    const float* ap = aprow + (kc); \
    float4 v0 = *(const float4*)(ap); \
    float4 v1 = *(const float4*)(ap+4); \
    float4 v2 = *(const float4*)(ap+8); \
    float4 v3 = *(const float4*)(ap+12); \
    uint4 pa, pb; \
    pa.x = f2bf(v0.x) | ((unsigned)f2bf(v0.y)<<16); \
    pa.y = f2bf(v0.z) | ((unsigned)f2bf(v0.w)<<16); \
    pa.z = f2bf(v1.x) | ((unsigned)f2bf(v1.y)<<16); \
    pa.w = f2bf(v1.z) | ((unsigned)f2bf(v1.w)<<16); \
    pb.x = f2bf(v2.x) | ((unsigned)f2bf(v2.y)<<16); \
    pb.y = f2bf(v2.z) | ((unsigned)f2bf(v2.w)<<16); \
    pb.z = f2bf(v3.x) | ((unsigned)f2bf(v3.y)<<16); \
    pb.w = f2bf(v3.z) | ((unsigned)f2bf(v3.w)<<16); \
    *(uint4*)&Al[buf][srow*LSTR + shalf*16] = pa; \
    *(uint4*)&Al[buf][srow*LSTR + shalf*16 + 8] = pb; \
    *(uint4*)&Bl[buf][bn*LSTR + bseg*8] = *(const uint4*)&Wt[bn*FIN + (kc) + bseg*8]; \
  } while(0)

  STAGE(0, 0);
  __syncthreads();

  #pragma unroll 1
  for(int step = 0; step < FIN/BK; ++step){
    int buf = step & 1;
    if(step + 1 < FIN/BK) STAGE(buf^1, (step+1)*BK);
    frag_ab af[2], bfr[4];
    #pragma unroll
    for(int i=0;i<2;i++) af[i] = *(const frag_ab*)&Al[buf][(w*32 + i*16 + fr)*LSTR + kg*8];
    #pragma unroll
    for(int j=0;j<4;j++) bfr[j] = *(const frag_ab*)&Bl[buf][(j*16 + fr)*LSTR + kg*8];
    #pragma unroll
    for(int i=0;i<2;i++)
      #pragma unroll
      for(int j=0;j<4;j++)
        acc[i][j] = __builtin_amdgcn_mfma_f32_16x16x32_bf16(af[i], bfr[j], acc[i][j], 0, 0, 0);
    __syncthreads();
  }

  #pragma unroll
  for(int i=0;i<2;i++){
    int crow = row0 + w*32 + i*16 + kg*4;
    #pragma unroll
    for(int j=0;j<4;j++){
      int ccol = j*16 + fr;
      #pragma unroll
      for(int r=0;r<4;r++){
        if(crow + r < M) Out[(size_t)(crow+r)*HDIM + ccol] = f2bf(acc[i][j][r]);
      }
    }
  }
  #undef STAGE
}

// ---------------- tiled f32 GEMM (layers 2,3): Outbf[M x C] = A[M x K] @ W[K x C] ----------------
template<int K, int C>
__global__ __launch_bounds__(256) void k_gemm(const float* __restrict__ A, const float* __restrict__ W,
                                              unsigned short* __restrict__ Out, int M){
  __shared__ float As[64][68];
  __shared__ float Ws[64][68];
  int t = threadIdx.x;
  int row0 = blockIdx.x * 64;
  float acc[4][4] = {{0.f}};
  int tr = (t >> 4) * 4;
  int tc = (t & 15) * 4;
  int arow = t >> 2;
  int acol = (t & 3) * 16;

  for(int kc = 0; kc < K; kc += 64){
    int rg = row0 + arow; if(rg >= M) rg = M-1;
    #pragma unroll
    for(int j=0;j<4;j++){
      *(float4*)&As[arow][acol + 4*j] = *(const float4*)&A[(size_t)rg*K + kc + acol + 4*j];
    }
    #pragma unroll
    for(int j=0;j<16;j++){
      int c = acol + j;
      Ws[arow][c] = (c < C) ? W[(kc + arow)*C + c] : 0.f;
    }
    __syncthreads();
    for(int kk=0; kk<64; kk+=4){
      float4 A4[4], W4[4];
      #pragma unroll
      for(int i=0;i<4;i++) A4[i] = *(float4*)&As[tr+i][kk];
      #pragma unroll
      for(int q=0;q<4;q++) W4[q] = *(float4*)&Ws[kk+q][tc];
      #pragma unroll
      for(int i=0;i<4;i++){
        float4 a = A4[i];
        acc[i][0] += a.x*W4[0].x + a.y*W4[1].x + a.z*W4[2].x + a.w*W4[3].x;
        acc[i][1] += a.x*W4[0].y + a.y*W4[1].y + a.z*W4[2].y + a.w*W4[3].y;
        acc[i][2] += a.x*W4[0].z + a.y*W4[1].z + a.z*W4[2].z + a.w*W4[3].z;
        acc[i][3] += a.x*W4[0].w + a.y*W4[1].w + a.z*W4[2].w + a.w*W4[3].w;
      }
    }
    __syncthreads();
  }
  #pragma unroll
  for(int i=0;i<4;i++){
    int r = row0 + tr + i;
    if(r >= M) continue;
    #pragma unroll
    for(int j=0;j<4;j++){
      int c = tc + j;
      if(c < C) Out[(size_t)r*C + c] = f2bf(acc[i][j]);
    }
  }
}

// ---------------- per-node attention coefficients (bf16 h) ----------------
template<int HEADS, int DIM>
__global__ void k_att(const unsigned short* __restrict__ h, const float* __restrict__ a_src,
                      const float* __restrict__ a_dst, float* __restrict__ as_o, float* __restrict__ ad_o){
  int gid = blockIdx.x*256 + threadIdx.x;
  int node = gid >> 6, lane = gid & 63;
  if(node >= NN) return;
  constexpr int HD = HEADS*DIM;
  float v = 0.f, asc = 0.f, adc = 0.f;
  if(lane < HD){ v = bf2f(h[(size_t)node*HD + lane]); asc = a_src[lane]; adc = a_dst[lane]; }
  float s1 = v*asc, s2 = v*adc;
  if(HEADS == 8){
    #pragma unroll
    for(int m=1;m<8;m<<=1){ s1 += __shfl_xor(s1,m); s2 += __shfl_xor(s2,m); }
    if((lane & 7) == 0){ as_o[node*8 + (lane>>3)] = s1; ad_o[node*8 + (lane>>3)] = s2; }
  } else {
    #pragma unroll
    for(int m=1;m<64;m<<=1){ s1 += __shfl_xor(s1,m); s2 += __shfl_xor(s2,m); }
    if(lane == 0){ as_o[node] = s1; ad_o[node] = s2; }
  }
}

// ---------------- aggregation: 2 edges per wave, bf16 h gather ----------------
// lane = (eh<<5)|fl : eh = edge-of-pair, fl = feature-pair index (2 features/lane).
// Each 32-lane half runs an independent online softmax over its edge subset;
// states merged at the end via shfl_xor(32).
template<int HEADS, int DIM, bool DO_ELU, bool DO_LSM>
__global__ __launch_bounds__(256) void k_agg(const unsigned short* __restrict__ hbf, const int* __restrict__ rp,
                      const int* __restrict__ col,
                      const float* __restrict__ as_, const float* __restrict__ ad_,
                      const float* __restrict__ bias, float* __restrict__ out){
  int gid = blockIdx.x*256 + threadIdx.x;
  int node = gid >> 6, lane = gid & 63;
  if(node >= NN) return;
  constexpr int HD = HEADS*DIM;
  constexpr int HW = HD/2;
  int eh = lane >> 5;
  int fl = lane & 31;
  bool act = fl < HW;
  int f0 = fl*2;
  int hidx = act ? (f0 / DIM) : 0;
  int beg = rp[node], end = rp[node+1];
  int deg = end - beg;
  float adn = ad_[node*HEADS + hidx];
  float m = -1e38f, s = 0.f, acc0 = 0.f, acc1 = 0.f;

  for(int base = 0; base < deg; base += 64){
    int cnt = deg - base; if(cnt > 64) cnt = 64;
    int idx = 0;
    if(lane < cnt) idx = col[beg + base + lane];
    for(int j = 0; j < cnt; j += 8){
      int sn[4];
      #pragma unroll
      for(int q=0;q<4;q++) sn[q] = __shfl(idx, j + 2*q + eh);
      float ea[4];
      #pragma unroll
      for(int q=0;q<4;q++) ea[q] = as_[sn[q]*HEADS + hidx];
      unsigned hv[4];
      #pragma unroll
      for(int q=0;q<4;q++) hv[q] = act ? *(const unsigned*)&hbf[(size_t)sn[q]*HD + f0] : 0u;
      float e[4];
      #pragma unroll
      for(int q=0;q<4;q++){
        float tv = ea[q] + adn;
        tv = (tv > 0.f) ? tv : 0.2f*tv;
        e[q] = (j + 2*q + eh < cnt) ? tv : -INFINITY;
      }
      float gm = fmaxf(fmaxf(fmaxf(e[0],e[1]), fmaxf(e[2],e[3])), m);
      float c  = __expf(m - gm);
      float p[4];
      #pragma unroll
      for(int q=0;q<4;q++) p[q] = __expf(e[q] - gm);
      s = s*c + ((p[0]+p[1]) + (p[2]+p[3]));
      acc0 *= c; acc1 *= c;
      #pragma unroll
      for(int q=0;q<4;q++){
        union { unsigned u; float f; } lo, hi;
        lo.u = hv[q] << 16;
        hi.u = hv[q] & 0xFFFF0000u;
        acc0 += p[q]*lo.f;
        acc1 += p[q]*hi.f;
      }
      m = gm;
    }
  }

  // merge the two half-wave softmax states
  float mo  = __shfl_xor(m, 32);
  float so  = __shfl_xor(s, 32);
  float a0o = __shfl_xor(acc0, 32);
  float a1o = __shfl_xor(acc1, 32);
  float mm  = fmaxf(m, mo);
  float cs  = __expf(m - mm), co = __expf(mo - mm);
  s    = s*cs + so*co;
  acc0 = acc0*cs + a0o*co;
  acc1 = acc1*cs + a1o*co;

  float inv = 1.f/s;
  float o0 = acc0*inv + (act ? bias[f0]   : 0.f);
  float o1 = acc1*inv + (act ? bias[f0+1] : 0.f);
  if(DO_ELU){
    o0 = (o0 > 0.f) ? o0 : expm1f(o0);
    o1 = (o1 > 0.f) ? o1 : expm1f(o1);
  }
  if(!DO_LSM){
    if(act && eh == 0){
      out[(size_t)node*HD + f0]   = o0;
      out[(size_t)node*HD + f0+1] = o1;
    }
  } else {
    float vmax = act ? fmaxf(o0, o1) : -INFINITY;
    #pragma unroll
    for(int mm2=1; mm2<32; mm2<<=1) vmax = fmaxf(vmax, __shfl_xor(vmax, mm2));
    float ex = act ? (expf(o0 - vmax) + expf(o1 - vmax)) : 0.f;
    #pragma unroll
    for(int mm2=1; mm2<32; mm2<<=1) ex += __shfl_xor(ex, mm2);
    float lg = logf(ex);
    if(act && eh == 0){
      out[(size_t)node*HD + f0]   = o0 - vmax - lg;
      out[(size_t)node*HD + f0+1] = o1 - vmax - lg;
    }
  }
}

// ---------------- launch ----------------
static inline size_t alignup(size_t x){ return (x + 255) & ~(size_t)255; }

extern "C" void kernel_launch(void* const* d_in, const int* in_sizes, int n_in,
                              void* d_out, int out_size, void* d_ws, size_t ws_size,
                              hipStream_t stream){
  const float* x      = (const float*)d_in[0];
  const int*   ei     = (const int*)d_in[1];
  const float* W1     = (const float*)d_in[2];
  const float* asrc1  = (const float*)d_in[3];
  const float* adst1  = (const float*)d_in[4];
  const float* b1     = (const float*)d_in[5];
  const float* W2     = (const float*)d_in[6];
  const float* asrc2  = (const float*)d_in[7];
  const float* adst2  = (const float*)d_in[8];
  const float* b2     = (const float*)d_in[9];
  const float* W3     = (const float*)d_in[10];
  const float* asrc3  = (const float*)d_in[11];
  const float* adst3  = (const float*)d_in[12];
  const float* b3     = (const float*)d_in[13];
  const int* src = ei;
  const int* dst = ei + EE;

  char* w = (char*)d_ws;
  int* rp     = (int*)w;              w += alignup((size_t)(NN+1)*4);
  int* bcnt   = (int*)w;              w += alignup((size_t)NBUK*4);
  int* bbase  = (int*)w;              w += alignup((size_t)(NBUK+1)*4);
  int* bcur   = (int*)w;              w += alignup((size_t)NBUK*4);
  unsigned short* Wt = (unsigned short*)w; w += alignup((size_t)FIN*HDIM*2);
  int* col    = (int*)w;              w += alignup((size_t)ET*4);
  unsigned short* hAb = (unsigned short*)w; w += alignup((size_t)NN*HDIM*2 + 256);
  float* hB   = (float*)w;            w += alignup((size_t)NN*HDIM*4);   // also pbuf (ET ints = 13.2MB <= 25.6MB)
  unsigned short* hCb = (unsigned short*)w; w += alignup((size_t)NN*NCLS*2 + 256);
  float* asA  = (float*)w;            w += alignup((size_t)NN*8*4);
  float* adA  = (float*)w;            w += alignup((size_t)NN*8*4);
  int* pbuf   = (int*)hB;

  dim3 blk(256);
  int gWav  = (NN*64 + 255)/256;
  int gGemm = (NN + 63)/64;
  int gG1   = (NN + BM - 1)/BM;
  int gBuk  = (ET + EPB - 1)/EPB;

  // CSR build (bucket sort)
  k_zeroB<<<2, blk, 0, stream>>>(bcnt);
  k_bcount<<<gBuk, blk, 0, stream>>>(dst, bcnt);
  k_bscan<<<1, dim3(NBUK), 0, stream>>>(bcnt, bbase, bcur);
  k_bucket<<<gBuk, blk, 0, stream>>>(src, dst, bcur, pbuf);
  k_bfinal<<<NBUK_USED, blk, 0, stream>>>(bbase, pbuf, rp, col);

  // layer 1 (bf16 MFMA GEMM -> bf16 h)
  k_cvtW<<<(FIN*HDIM + 255)/256, blk, 0, stream>>>(W1, Wt);
  k_gemm1<<<gG1, blk, 0, stream>>>(x, Wt, hAb, NN);
  k_att<8,8><<<gWav, blk, 0, stream>>>(hAb, asrc1, adst1, asA, adA);
  k_agg<8,8,true,false><<<gWav, blk, 0, stream>>>(hAb, rp, col, asA, adA, b1, hB);

  // layer 2
  k_gemm<HDIM, HDIM><<<gGemm, blk, 0, stream>>>(hB, W2, hAb, NN);
  k_att<8,8><<<gWav, blk, 0, stream>>>(hAb, asrc2, adst2, asA, adA);
  k_agg<8,8,true,false><<<gWav, blk, 0, stream>>>(hAb, rp, col, asA, adA, b2, hB);

  // layer 3
  k_gemm<HDIM, NCLS><<<gGemm, blk, 0, stream>>>(hB, W3, hCb, NN);
  k_att<1,NCLS><<<gWav, blk, 0, stream>>>(hCb, asrc3, adst3, asA, adA);
  k_agg<1,NCLS,false,true><<<gWav, blk, 0, stream>>>(hCb, rp, col, asA, adA, b3, (float*)d_out);
}

// Round 6
// 431.659 us; speedup vs baseline: 4.0317x; 1.3957x over previous
//
#include <hip/hip_runtime.h>
#include <math.h>

#define NN 100000
#define EE 3200000
#define ET 3300000   // EE + NN self loops
#define FIN 512
#define HDIM 64
#define NCLS 40

// bucket sort params
#define NBUK 512
#define NPB 196          // nodes per bucket; buckets 0..510 used
#define NBUK_USED 511
#define EPB 4096
#define EPT 16
#define CAP 8192         // per-bucket slot capacity (mean 6458, sigma~80)

typedef __attribute__((ext_vector_type(8))) short frag_ab;
typedef __attribute__((ext_vector_type(4))) float frag_cd;

__device__ inline unsigned short f2bf(float f){
  union { float f; unsigned int u; } x; x.f = f;
  unsigned int u = x.u;
  unsigned int r = u + 0x7FFF + ((u >> 16) & 1);
  return (unsigned short)(r >> 16);
}
__device__ inline float bflo(unsigned u){
  union { unsigned u; float f; } x; x.u = u << 16; return x.f;
}
__device__ inline float bfhi(unsigned u){
  union { unsigned u; float f; } x; x.u = u & 0xFFFF0000u; return x.f;
}
__device__ inline float bf2f(unsigned short u){
  union { unsigned int u; float f; } x; x.u = ((unsigned int)u) << 16;
  return x.f;
}

// ---------------- CSR build: bucket append + compact ----------------
__global__ void k_zeroB(int* bcur){
  int t = blockIdx.x*256 + threadIdx.x;
  if(t < NBUK) bcur[t] = 0;
}

__global__ __launch_bounds__(256) void k_bucket(const int* __restrict__ src, const int* __restrict__ dst,
                                                int* __restrict__ bcur, int* __restrict__ pbuf){
  __shared__ int lcnt[NBUK];
  __shared__ int lbase[NBUK];
  int t = threadIdx.x;
  for(int i=t;i<NBUK;i+=256) lcnt[i]=0;
  __syncthreads();
  int base = blockIdx.x*EPB + t;
  int bk[EPT], rk[EPT], pk[EPT];
  #pragma unroll
  for(int j=0;j<EPT;j++){
    int e = base + j*256;
    bk[j] = -1;
    if(e < ET){
      int s, d;
      if(e < EE){ s = src[e]; d = dst[e]; } else { s = e - EE; d = s; }
      int b = d / NPB;
      bk[j] = b;
      pk[j] = s | ((d - b*NPB) << 17);
      rk[j] = atomicAdd(&lcnt[b], 1);
    }
  }
  __syncthreads();
  for(int i=t;i<NBUK;i+=256){
    int v = lcnt[i];
    lbase[i] = v ? atomicAdd(&bcur[i], v) : 0;
  }
  __syncthreads();
  #pragma unroll
  for(int j=0;j<EPT;j++){
    if(bk[j] >= 0){
      int pos = lbase[bk[j]] + rk[j];
      if(pos < CAP) pbuf[(size_t)bk[j]*CAP + pos] = pk[j];
    }
  }
}

__global__ void k_bscan(const int* __restrict__ bcur, int* __restrict__ bbase){
  __shared__ int lds[NBUK];
  int t = threadIdx.x;                 // 512 threads
  int v = (t < NBUK_USED) ? bcur[t] : 0;
  lds[t] = v;
  __syncthreads();
  for(int off=1; off<NBUK; off<<=1){
    int x = 0;
    if(t >= off) x = lds[t-off];
    __syncthreads();
    if(t >= off) lds[t] += x;
    __syncthreads();
  }
  bbase[t] = lds[t] - v;   // exclusive; bbase[511] == ET
}

__global__ __launch_bounds__(256) void k_bfinal(const int* __restrict__ bbase, const int* __restrict__ pbuf,
                                                int* __restrict__ rp, int* __restrict__ col){
  __shared__ int cnt[NPB];
  int b = blockIdx.x, t = threadIdx.x;
  int beg = bbase[b];
  int cntb = bbase[b+1] - beg;
  const int* pb = pbuf + (size_t)b*CAP;
  for(int i=t;i<NPB;i+=256) cnt[i]=0;
  __syncthreads();
  for(int i=t; i<cntb; i+=256){
    int dloc = pb[i] >> 17;
    atomicAdd(&cnt[dloc], 1);
  }
  __syncthreads();
  if(t < 64){
    int vals[4]; int sum = 0;
    #pragma unroll
    for(int j=0;j<4;j++){ int idx = t*4+j; int v = (idx<NPB)?cnt[idx]:0; vals[j]=v; sum+=v; }
    int incl = sum;
    #pragma unroll
    for(int off=1; off<64; off<<=1){
      int x = __shfl_up(incl, off);
      if(t >= off) incl += x;
    }
    int run = incl - sum;
    #pragma unroll
    for(int j=0;j<4;j++){
      int idx = t*4+j;
      if(idx < NPB){ int v = vals[j]; cnt[idx] = run; run += v; }
    }
  }
  __syncthreads();
  int node0 = b*NPB;
  int nloc = NN - node0; if(nloc > NPB) nloc = NPB;
  for(int i=t;i<nloc;i+=256){
    int g = beg + cnt[i];
    rp[node0 + i] = g;
    cnt[i] = g;
  }
  if(b == 0 && t == 0) rp[NN] = ET;
  __syncthreads();
  for(int i=t; i<cntb; i+=256){
    int v = pb[i];
    int s = v & 0x1FFFF;
    int dloc = v >> 17;
    int pos = atomicAdd(&cnt[dloc], 1);
    col[pos] = s;
  }
}

// ---------------- W[K x C] -> bf16 transposed+padded Wt[64][K] ----------------
__global__ void k_cvtW(const float* __restrict__ W, unsigned short* __restrict__ Wt, int K, int C){
  int i = blockIdx.x*256 + threadIdx.x;
  if(i >= 64*K) return;
  int n = i / K, k = i - n*K;
  Wt[i] = (n < C) ? f2bf(W[k*C + n]) : (unsigned short)0;
}

// ---------------- GEMM1: f32 A -> bf16 MFMA, Outbf[M x 64] = A[M x 512] @ W ----------------
#define BM 128
#define BK 32
#define LSTR 40
__global__ __launch_bounds__(256) void k_gemm1(const float* __restrict__ A, const unsigned short* __restrict__ Wt,
                                               unsigned short* __restrict__ Out, int M){
  __shared__ __attribute__((aligned(16))) unsigned short Al[2][BM*LSTR];
  __shared__ __attribute__((aligned(16))) unsigned short Bl[2][64*LSTR];
  int t = threadIdx.x;
  int w = t >> 6, l = t & 63;
  int row0 = blockIdx.x * BM;

  int srow = t >> 1;
  int shalf = t & 1;
  int bn = t >> 2;
  int bseg = t & 3;

  int fr = l & 15, kg = l >> 4;

  frag_cd acc[2][4];
  #pragma unroll
  for(int i=0;i<2;i++)
    #pragma unroll
    for(int j=0;j<4;j++) acc[i][j] = (frag_cd){0.f,0.f,0.f,0.f};

  int rg = row0 + srow; if(rg >= M) rg = M-1;
  const float* aprow = &A[(size_t)rg*FIN + shalf*16];

  #define STAGE(buf, kc) do { \
    const float* ap = aprow + (kc); \
    float4 v0 = *(const float4*)(ap); \
    float4 v1 = *(const float4*)(ap+4); \
    float4 v2 = *(const float4*)(ap+8); \
    float4 v3 = *(const float4*)(ap+12); \
    uint4 pa, pb; \
    pa.x = f2bf(v0.x) | ((unsigned)f2bf(v0.y)<<16); \
    pa.y = f2bf(v0.z) | ((unsigned)f2bf(v0.w)<<16); \
    pa.z = f2bf(v1.x) | ((unsigned)f2bf(v1.y)<<16); \
    pa.w = f2bf(v1.z) | ((unsigned)f2bf(v1.w)<<16); \
    pb.x = f2bf(v2.x) | ((unsigned)f2bf(v2.y)<<16); \
    pb.y = f2bf(v2.z) | ((unsigned)f2bf(v2.w)<<16); \
    pb.z = f2bf(v3.x) | ((unsigned)f2bf(v3.y)<<16); \
    pb.w = f2bf(v3.z) | ((unsigned)f2bf(v3.w)<<16); \
    *(uint4*)&Al[buf][srow*LSTR + shalf*16] = pa; \
    *(uint4*)&Al[buf][srow*LSTR + shalf*16 + 8] = pb; \
    *(uint4*)&Bl[buf][bn*LSTR + bseg*8] = *(const uint4*)&Wt[bn*FIN + (kc) + bseg*8]; \
  } while(0)

  STAGE(0, 0);
  __syncthreads();

  #pragma unroll 1
  for(int step = 0; step < FIN/BK; ++step){
    int buf = step & 1;
    if(step + 1 < FIN/BK) STAGE(buf^1, (step+1)*BK);
    frag_ab af[2], bfr[4];
    #pragma unroll
    for(int i=0;i<2;i++) af[i] = *(const frag_ab*)&Al[buf][(w*32 + i*16 + fr)*LSTR + kg*8];
    #pragma unroll
    for(int j=0;j<4;j++) bfr[j] = *(const frag_ab*)&Bl[buf][(j*16 + fr)*LSTR + kg*8];
    #pragma unroll
    for(int i=0;i<2;i++)
      #pragma unroll
      for(int j=0;j<4;j++)
        acc[i][j] = __builtin_amdgcn_mfma_f32_16x16x32_bf16(af[i], bfr[j], acc[i][j], 0, 0, 0);
    __syncthreads();
  }

  #pragma unroll
  for(int i=0;i<2;i++){
    int crow = row0 + w*32 + i*16 + kg*4;
    #pragma unroll
    for(int j=0;j<4;j++){
      int ccol = j*16 + fr;
      #pragma unroll
      for(int r=0;r<4;r++){
        if(crow + r < M) Out[(size_t)(crow+r)*HDIM + ccol] = f2bf(acc[i][j][r]);
      }
    }
  }
  #undef STAGE
}

// ---------------- bf16 MFMA GEMM (layers 2,3): Outbf[M x C] = Abf[M x K] @ Wt[64][K] ----------------
template<int K, int C>
__global__ __launch_bounds__(256) void k_gemmb(const unsigned short* __restrict__ A,
                                               const unsigned short* __restrict__ Wt,
                                               unsigned short* __restrict__ Out, int M){
  constexpr int CT = (C + 15)/16;
  __shared__ __attribute__((aligned(16))) unsigned short Al[2][BM*LSTR];
  __shared__ __attribute__((aligned(16))) unsigned short Bl[2][64*LSTR];
  int t = threadIdx.x;
  int w = t >> 6, l = t & 63;
  int row0 = blockIdx.x * BM;

  int srow = t >> 1;
  int shalf = t & 1;
  int bn = t >> 2;
  int bseg = t & 3;

  int fr = l & 15, kg = l >> 4;

  frag_cd acc[2][CT];
  #pragma unroll
  for(int i=0;i<2;i++)
    #pragma unroll
    for(int j=0;j<CT;j++) acc[i][j] = (frag_cd){0.f,0.f,0.f,0.f};

  int rg = row0 + srow; if(rg >= M) rg = M-1;
  const unsigned short* aprow = &A[(size_t)rg*K + shalf*16];

  #define STAGEB(buf, kc) do { \
    *(uint4*)&Al[buf][srow*LSTR + shalf*16]     = *(const uint4*)(aprow + (kc)); \
    *(uint4*)&Al[buf][srow*LSTR + shalf*16 + 8] = *(const uint4*)(aprow + (kc) + 8); \
    *(uint4*)&Bl[buf][bn*LSTR + bseg*8] = *(const uint4*)&Wt[bn*K + (kc) + bseg*8]; \
  } while(0)

  // A rows are K shorts; shalf*16 + 8 stays within the 32-col k-slice? No:
  // shalf in {0,1} gives cols 0..15 / 16..31 of the slice; +8 is within 16. OK.

  STAGEB(0, 0);
  __syncthreads();

  #pragma unroll 1
  for(int step = 0; step < K/BK; ++step){
    int buf = step & 1;
    if(step + 1 < K/BK) STAGEB(buf^1, (step+1)*BK);
    frag_ab af[2], bfr[CT];
    #pragma unroll
    for(int i=0;i<2;i++) af[i] = *(const frag_ab*)&Al[buf][(w*32 + i*16 + fr)*LSTR + kg*8];
    #pragma unroll
    for(int j=0;j<CT;j++) bfr[j] = *(const frag_ab*)&Bl[buf][(j*16 + fr)*LSTR + kg*8];
    #pragma unroll
    for(int i=0;i<2;i++)
      #pragma unroll
      for(int j=0;j<CT;j++)
        acc[i][j] = __builtin_amdgcn_mfma_f32_16x16x32_bf16(af[i], bfr[j], acc[i][j], 0, 0, 0);
    __syncthreads();
  }

  #pragma unroll
  for(int i=0;i<2;i++){
    int crow = row0 + w*32 + i*16 + kg*4;
    #pragma unroll
    for(int j=0;j<CT;j++){
      int ccol = j*16 + fr;
      if(ccol >= C) continue;
      #pragma unroll
      for(int r=0;r<4;r++){
        if(crow + r < M) Out[(size_t)(crow+r)*C + ccol] = f2bf(acc[i][j][r]);
      }
    }
  }
  #undef STAGEB
}

// ---------------- per-node attention coefficients (bf16 h) ----------------
template<int HEADS, int DIM>
__global__ void k_att(const unsigned short* __restrict__ h, const float* __restrict__ a_src,
                      const float* __restrict__ a_dst, float* __restrict__ as_o, float* __restrict__ ad_o){
  int gid = blockIdx.x*256 + threadIdx.x;
  int node = gid >> 6, lane = gid & 63;
  if(node >= NN) return;
  constexpr int HD = HEADS*DIM;
  float v = 0.f, asc = 0.f, adc = 0.f;
  if(lane < HD){ v = bf2f(h[(size_t)node*HD + lane]); asc = a_src[lane]; adc = a_dst[lane]; }
  float s1 = v*asc, s2 = v*adc;
  if(HEADS == 8){
    #pragma unroll
    for(int m=1;m<8;m<<=1){ s1 += __shfl_xor(s1,m); s2 += __shfl_xor(s2,m); }
    if((lane & 7) == 0){ as_o[node*8 + (lane>>3)] = s1; ad_o[node*8 + (lane>>3)] = s2; }
  } else {
    #pragma unroll
    for(int m=1;m<64;m<<=1){ s1 += __shfl_xor(s1,m); s2 += __shfl_xor(s2,m); }
    if(lane == 0){ as_o[node] = s1; ad_o[node] = s2; }
  }
}

// ---------------- aggregation: 4 edges per wave, 4 bf16 features/lane ----------------
// lane = (el<<4)|fl : el = edge slot (0..3), fl = feature quad (f0 = fl*4).
// Each 16-lane quarter runs an independent online softmax over its edge subset;
// states merged via shfl_xor(16) then shfl_xor(32).
template<int HEADS, int DIM, bool DO_ELU, bool DO_LSM>
__global__ __launch_bounds__(256) void k_agg(const unsigned short* __restrict__ hbf, const int* __restrict__ rp,
                      const int* __restrict__ col,
                      const float* __restrict__ as_, const float* __restrict__ ad_,
                      const float* __restrict__ bias, void* __restrict__ outp){
  int gid = blockIdx.x*256 + threadIdx.x;
  int node = gid >> 6, lane = gid & 63;
  if(node >= NN) return;
  constexpr int HD = HEADS*DIM;
  int el = lane >> 4;
  int fl = lane & 15;
  int f0 = fl*4;
  bool act = f0 < HD;
  int hidx = act ? (f0 / DIM) : 0;
  int beg = rp[node], end = rp[node+1];
  int deg = end - beg;
  float adn = ad_[node*HEADS + hidx];
  float m = -1e38f, s = 0.f;
  float a0 = 0.f, a1 = 0.f, a2 = 0.f, a3 = 0.f;

  for(int base = 0; base < deg; base += 64){
    int cnt = deg - base; if(cnt > 64) cnt = 64;
    int idx = 0;
    if(lane < cnt) idx = col[beg + base + lane];
    for(int j = 0; j < cnt; j += 8){
      int sn0 = __shfl(idx, j + el);
      int sn1 = __shfl(idx, j + 4 + el);
      bool v0 = (j + el) < cnt;
      bool v1 = (j + 4 + el) < cnt;
      float ea0 = as_[sn0*HEADS + hidx];
      float ea1 = as_[sn1*HEADS + hidx];
      uint2 h0 = act ? *(const uint2*)&hbf[(size_t)sn0*HD + f0] : make_uint2(0u,0u);
      uint2 h1 = act ? *(const uint2*)&hbf[(size_t)sn1*HD + f0] : make_uint2(0u,0u);
      float e0 = ea0 + adn; e0 = (e0 > 0.f) ? e0 : 0.2f*e0; e0 = v0 ? e0 : -INFINITY;
      float e1 = ea1 + adn; e1 = (e1 > 0.f) ? e1 : 0.2f*e1; e1 = v1 ? e1 : -INFINITY;
      float gm = fmaxf(fmaxf(e0, e1), m);
      float c  = __expf(m - gm);
      float p0 = __expf(e0 - gm);
      float p1 = __expf(e1 - gm);
      s = s*c + p0 + p1;
      a0 = a0*c + p0*bflo(h0.x) + p1*bflo(h1.x);
      a1 = a1*c + p0*bfhi(h0.x) + p1*bfhi(h1.x);
      a2 = a2*c + p0*bflo(h0.y) + p1*bflo(h1.y);
      a3 = a3*c + p0*bfhi(h0.y) + p1*bfhi(h1.y);
      m = gm;
    }
  }

  // merge the 4 quarter-wave softmax states
  #pragma unroll
  for(int wd=16; wd<=32; wd<<=1){
    float mo  = __shfl_xor(m, wd);
    float so  = __shfl_xor(s, wd);
    float b0  = __shfl_xor(a0, wd);
    float b1  = __shfl_xor(a1, wd);
    float b2  = __shfl_xor(a2, wd);
    float b3  = __shfl_xor(a3, wd);
    float mm2 = fmaxf(m, mo);
    float cs  = __expf(m - mm2), co = __expf(mo - mm2);
    s  = s*cs  + so*co;
    a0 = a0*cs + b0*co;
    a1 = a1*cs + b1*co;
    a2 = a2*cs + b2*co;
    a3 = a3*cs + b3*co;
    m = mm2;
  }

  float inv = 1.f/s;
  float o0 = a0*inv, o1 = a1*inv, o2 = a2*inv, o3 = a3*inv;
  if(act){
    float4 bb = *(const float4*)&bias[f0];
    o0 += bb.x; o1 += bb.y; o2 += bb.z; o3 += bb.w;
  }
  if(DO_ELU){
    o0 = (o0 > 0.f) ? o0 : expm1f(o0);
    o1 = (o1 > 0.f) ? o1 : expm1f(o1);
    o2 = (o2 > 0.f) ? o2 : expm1f(o2);
    o3 = (o3 > 0.f) ? o3 : expm1f(o3);
  }
  if(!DO_LSM){
    if(act && el == 0){
      unsigned short* ob = (unsigned short*)outp;
      uint2 pk;
      pk.x = f2bf(o0) | ((unsigned)f2bf(o1) << 16);
      pk.y = f2bf(o2) | ((unsigned)f2bf(o3) << 16);
      *(uint2*)&ob[(size_t)node*HD + f0] = pk;
    }
  } else {
    float vmax = act ? fmaxf(fmaxf(o0,o1), fmaxf(o2,o3)) : -INFINITY;
    #pragma unroll
    for(int mm2=1; mm2<16; mm2<<=1) vmax = fmaxf(vmax, __shfl_xor(vmax, mm2));
    float ex = act ? (expf(o0-vmax) + expf(o1-vmax) + expf(o2-vmax) + expf(o3-vmax)) : 0.f;
    #pragma unroll
    for(int mm2=1; mm2<16; mm2<<=1) ex += __shfl_xor(ex, mm2);
    float lg = logf(ex);
    if(act && el == 0){
      float* of = (float*)outp;
      float4 r;
      r.x = o0 - vmax - lg; r.y = o1 - vmax - lg;
      r.z = o2 - vmax - lg; r.w = o3 - vmax - lg;
      *(float4*)&of[(size_t)node*HD + f0] = r;
    }
  }
}

// ---------------- launch ----------------
static inline size_t alignup(size_t x){ return (x + 255) & ~(size_t)255; }

extern "C" void kernel_launch(void* const* d_in, const int* in_sizes, int n_in,
                              void* d_out, int out_size, void* d_ws, size_t ws_size,
                              hipStream_t stream){
  const float* x      = (const float*)d_in[0];
  const int*   ei     = (const int*)d_in[1];
  const float* W1     = (const float*)d_in[2];
  const float* asrc1  = (const float*)d_in[3];
  const float* adst1  = (const float*)d_in[4];
  const float* b1     = (const float*)d_in[5];
  const float* W2     = (const float*)d_in[6];
  const float* asrc2  = (const float*)d_in[7];
  const float* adst2  = (const float*)d_in[8];
  const float* b2     = (const float*)d_in[9];
  const float* W3     = (const float*)d_in[10];
  const float* asrc3  = (const float*)d_in[11];
  const float* adst3  = (const float*)d_in[12];
  const float* b3     = (const float*)d_in[13];
  const int* src = ei;
  const int* dst = ei + EE;

  char* w = (char*)d_ws;
  int* rp     = (int*)w;              w += alignup((size_t)(NN+1)*4);
  int* bbase  = (int*)w;              w += alignup((size_t)(NBUK+1)*4);
  int* bcur   = (int*)w;              w += alignup((size_t)NBUK*4);
  unsigned short* Wt1 = (unsigned short*)w; w += alignup((size_t)64*FIN*2);
  unsigned short* Wt2 = (unsigned short*)w; w += alignup((size_t)64*HDIM*2);
  unsigned short* Wt3 = (unsigned short*)w; w += alignup((size_t)64*HDIM*2);
  int* col    = (int*)w;              w += alignup((size_t)ET*4);
  int* pbuf   = (int*)w;              w += alignup((size_t)NBUK*CAP*4);
  unsigned short* hAb = (unsigned short*)w; w += alignup((size_t)NN*HDIM*2 + 256);
  unsigned short* hBb = (unsigned short*)w; w += alignup((size_t)NN*HDIM*2 + 256);
  unsigned short* hCb = (unsigned short*)w; w += alignup((size_t)NN*NCLS*2 + 256);
  float* asA  = (float*)w;            w += alignup((size_t)NN*8*4);
  float* adA  = (float*)w;            w += alignup((size_t)NN*8*4);

  dim3 blk(256);
  int gWav  = (NN*64 + 255)/256;
  int gG1   = (NN + BM - 1)/BM;
  int gBuk  = (ET + EPB - 1)/EPB;

  // CSR build
  k_zeroB<<<2, blk, 0, stream>>>(bcur);
  k_bucket<<<gBuk, blk, 0, stream>>>(src, dst, bcur, pbuf);
  k_bscan<<<1, dim3(NBUK), 0, stream>>>(bcur, bbase);
  k_bfinal<<<NBUK_USED, blk, 0, stream>>>(bbase, pbuf, rp, col);

  // weight converts
  k_cvtW<<<(64*FIN + 255)/256, blk, 0, stream>>>(W1, Wt1, FIN, HDIM);
  k_cvtW<<<(64*HDIM + 255)/256, blk, 0, stream>>>(W2, Wt2, HDIM, HDIM);
  k_cvtW<<<(64*HDIM + 255)/256, blk, 0, stream>>>(W3, Wt3, HDIM, NCLS);

  // layer 1
  k_gemm1<<<gG1, blk, 0, stream>>>(x, Wt1, hAb, NN);
  k_att<8,8><<<gWav, blk, 0, stream>>>(hAb, asrc1, adst1, asA, adA);
  k_agg<8,8,true,false><<<gWav, blk, 0, stream>>>(hAb, rp, col, asA, adA, b1, hBb);

  // layer 2
  k_gemmb<HDIM, HDIM><<<gG1, blk, 0, stream>>>(hBb, Wt2, hAb, NN);
  k_att<8,8><<<gWav, blk, 0, stream>>>(hAb, asrc2, adst2, asA, adA);
  k_agg<8,8,true,false><<<gWav, blk, 0, stream>>>(hAb, rp, col, asA, adA, b2, hBb);

  // layer 3
  k_gemmb<HDIM, NCLS><<<gG1, blk, 0, stream>>>(hBb, Wt3, hCb, NN);
  k_att<1,NCLS><<<gWav, blk, 0, stream>>>(hCb, asrc3, adst3, asA, adA);
  k_agg<1,NCLS,false,true><<<gWav, blk, 0, stream>>>(hCb, rp, col, asA, adA, b3, d_out);
}

// Round 7
// 415.207 us; speedup vs baseline: 4.1915x; 1.0396x over previous
//
#include <hip/hip_runtime.h>
#include <math.h>

#define NN 100000
#define EE 3200000
#define ET 3300000   // EE + NN self loops
#define FIN 512
#define HDIM 64
#define NCLS 40

// bucket sort params
#define NBUK 512
#define NPB 196          // nodes per bucket; buckets 0..510 used
#define NBUK_USED 511
#define EPB 4096
#define EPT 16
#define CAP 8192         // per-bucket slot capacity (mean 6458, sigma~80)

typedef __attribute__((ext_vector_type(8))) short frag_ab;
typedef __attribute__((ext_vector_type(4))) float frag_cd;

#define CVTPK(dst, a, b) asm("v_cvt_pk_bf16_f32 %0, %1, %2" : "=v"(dst) : "v"(a), "v"(b))

__device__ inline unsigned short f2bf(float f){
  union { float f; unsigned int u; } x; x.f = f;
  unsigned int u = x.u;
  unsigned int r = u + 0x7FFF + ((u >> 16) & 1);
  return (unsigned short)(r >> 16);
}
__device__ inline float bflo(unsigned u){
  union { unsigned u; float f; } x; x.u = u << 16; return x.f;
}
__device__ inline float bfhi(unsigned u){
  union { unsigned u; float f; } x; x.u = u & 0xFFFF0000u; return x.f;
}

// ---------------- prep: weights -> bf16 transposed, scaled att vecs, zero bcur ----------------
// attv layout: [as1(64), ad1(64), as2(64), ad2(64), as3(48 pad), ad3(48 pad)] scaled by log2e
__global__ void k_prep(const float* __restrict__ W1, const float* __restrict__ W2, const float* __restrict__ W3,
                       const float* __restrict__ as1, const float* __restrict__ ad1,
                       const float* __restrict__ as2, const float* __restrict__ ad2,
                       const float* __restrict__ as3, const float* __restrict__ ad3,
                       unsigned short* __restrict__ Wt1, unsigned short* __restrict__ Wt2,
                       unsigned short* __restrict__ Wt3, float* __restrict__ attv, int* __restrict__ bcur){
  int i = blockIdx.x*256 + threadIdx.x;
  if(i < NBUK) bcur[i] = 0;
  if(i < 32768){
    int n = i >> 9, k = i & 511;
    Wt1[i] = f2bf(W1[k*HDIM + n]);
  } else if(i < 36864){
    int i2 = i - 32768; int n = i2 >> 6, k = i2 & 63;
    Wt2[i2] = f2bf(W2[k*HDIM + n]);
  } else if(i < 40960){
    int i3 = i - 36864; int n = i3 >> 6, k = i3 & 63;
    Wt3[i3] = (n < NCLS) ? f2bf(W3[k*NCLS + n]) : (unsigned short)0;
  } else if(i < 41312){
    int j = i - 40960;
    const float L2E = 1.4426950408889634f;
    float v;
    if(j < 64) v = as1[j]*L2E;
    else if(j < 128) v = ad1[j-64]*L2E;
    else if(j < 192) v = as2[j-128]*L2E;
    else if(j < 256) v = ad2[j-192]*L2E;
    else if(j < 304){ int q=j-256; v = (q<NCLS)? as3[q]*L2E : 0.f; }
    else { int q=j-304; v = (q<NCLS)? ad3[q]*L2E : 0.f; }
    attv[j] = v;
  }
}

// ---------------- CSR build: bucket append + compact ----------------
__global__ __launch_bounds__(256) void k_bucket(const int* __restrict__ src, const int* __restrict__ dst,
                                                int* __restrict__ bcur, int* __restrict__ pbuf){
  __shared__ int lcnt[NBUK];
  __shared__ int lbase[NBUK];
  int t = threadIdx.x;
  for(int i=t;i<NBUK;i+=256) lcnt[i]=0;
  __syncthreads();
  int base = blockIdx.x*EPB + t;
  int bk[EPT], rk[EPT], pk[EPT];
  #pragma unroll
  for(int j=0;j<EPT;j++){
    int e = base + j*256;
    bk[j] = -1;
    if(e < ET){
      int s, d;
      if(e < EE){ s = src[e]; d = dst[e]; } else { s = e - EE; d = s; }
      int b = d / NPB;
      bk[j] = b;
      pk[j] = s | ((d - b*NPB) << 17);
      rk[j] = atomicAdd(&lcnt[b], 1);
    }
  }
  __syncthreads();
  for(int i=t;i<NBUK;i+=256){
    int v = lcnt[i];
    lbase[i] = v ? atomicAdd(&bcur[i], v) : 0;
  }
  __syncthreads();
  #pragma unroll
  for(int j=0;j<EPT;j++){
    if(bk[j] >= 0){
      int pos = lbase[bk[j]] + rk[j];
      if(pos < CAP) pbuf[(size_t)bk[j]*CAP + pos] = pk[j];
    }
  }
}

__global__ void k_bscan(const int* __restrict__ bcur, int* __restrict__ bbase){
  __shared__ int lds[NBUK];
  int t = threadIdx.x;                 // 512 threads
  int v = (t < NBUK_USED) ? bcur[t] : 0;
  lds[t] = v;
  __syncthreads();
  for(int off=1; off<NBUK; off<<=1){
    int x = 0;
    if(t >= off) x = lds[t-off];
    __syncthreads();
    if(t >= off) lds[t] += x;
    __syncthreads();
  }
  bbase[t] = lds[t] - v;   // exclusive; bbase[511] == ET
}

__global__ __launch_bounds__(256) void k_bfinal(const int* __restrict__ bbase, const int* __restrict__ pbuf,
                                                int* __restrict__ rp, int* __restrict__ col){
  __shared__ int cnt[NPB];
  int b = blockIdx.x, t = threadIdx.x;
  int beg = bbase[b];
  int cntb = bbase[b+1] - beg;
  const int* pb = pbuf + (size_t)b*CAP;
  for(int i=t;i<NPB;i+=256) cnt[i]=0;
  __syncthreads();
  for(int i=t; i<cntb; i+=256){
    int dloc = pb[i] >> 17;
    atomicAdd(&cnt[dloc], 1);
  }
  __syncthreads();
  if(t < 64){
    int vals[4]; int sum = 0;
    #pragma unroll
    for(int j=0;j<4;j++){ int idx = t*4+j; int v = (idx<NPB)?cnt[idx]:0; vals[j]=v; sum+=v; }
    int incl = sum;
    #pragma unroll
    for(int off=1; off<64; off<<=1){
      int x = __shfl_up(incl, off);
      if(t >= off) incl += x;
    }
    int run = incl - sum;
    #pragma unroll
    for(int j=0;j<4;j++){
      int idx = t*4+j;
      if(idx < NPB){ int v = vals[j]; cnt[idx] = run; run += v; }
    }
  }
  __syncthreads();
  int node0 = b*NPB;
  int nloc = NN - node0; if(nloc > NPB) nloc = NPB;
  for(int i=t;i<nloc;i+=256){
    int g = beg + cnt[i];
    rp[node0 + i] = g;
    cnt[i] = g;
  }
  if(b == 0 && t == 0) rp[NN] = ET;
  __syncthreads();
  for(int i=t; i<cntb; i+=256){
    int v = pb[i];
    int s = v & 0x1FFFF;
    int dloc = v >> 17;
    int pos = atomicAdd(&cnt[dloc], 1);
    col[pos] = s;
  }
}

// ---------------- fused attention-coefficient epilogues ----------------
// C/D frag: value acc[i][j][r] = Out[rowbase + i*16 + kg*4 + r][j*16 + fr]
// HEADS=8, DIM=8: head of col = 2j + (fr>>3); reduce over d=fr&7.
// Stored PERMUTED: as_o[row*8 + (fr>>3)*4 + j] -> head (2j + half) at pos half*4+j.
template<int CT>
__device__ inline void att_epi8(const frag_cd (&acc)[2][CT], int rowbase, int fr, int kg,
                                const float* __restrict__ asv, const float* __restrict__ adv,
                                float* __restrict__ as_o, float* __restrict__ ad_o, int M){
  float av[CT], dv[CT];
  #pragma unroll
  for(int j=0;j<CT;j++){ av[j]=asv[j*16+fr]; dv[j]=adv[j*16+fr]; }
  #pragma unroll
  for(int i=0;i<2;i++){
    #pragma unroll
    for(int r=0;r<4;r++){
      int row = rowbase + i*16 + kg*4 + r;
      float ps[CT], pd[CT];
      #pragma unroll
      for(int j=0;j<CT;j++){ float v = acc[i][j][r]; ps[j]=v*av[j]; pd[j]=v*dv[j]; }
      #pragma unroll
      for(int mk=1; mk<8; mk<<=1){
        #pragma unroll
        for(int j=0;j<CT;j++){ ps[j]+=__shfl_xor(ps[j],mk); pd[j]+=__shfl_xor(pd[j],mk); }
      }
      if((fr&7)==0 && row < M){
        int half = fr>>3;
        float4 s4; s4.x=ps[0]; s4.y=ps[1]; s4.z=ps[2]; s4.w=ps[3];
        float4 d4; d4.x=pd[0]; d4.y=pd[1]; d4.z=pd[2]; d4.w=pd[3];
        *(float4*)&as_o[row*8 + half*4] = s4;
        *(float4*)&ad_o[row*8 + half*4] = d4;
      }
    }
  }
}

// HEADS=1: full-row dot (cols padded with zero att weights)
template<int CT>
__device__ inline void att_epi1(const frag_cd (&acc)[2][CT], int rowbase, int fr, int kg,
                                const float* __restrict__ asv, const float* __restrict__ adv,
                                float* __restrict__ as_o, float* __restrict__ ad_o, int M){
  float av[CT], dv[CT];
  #pragma unroll
  for(int j=0;j<CT;j++){ av[j]=asv[j*16+fr]; dv[j]=adv[j*16+fr]; }
  #pragma unroll
  for(int i=0;i<2;i++){
    #pragma unroll
    for(int r=0;r<4;r++){
      int row = rowbase + i*16 + kg*4 + r;
      float ps=0.f, pd=0.f;
      #pragma unroll
      for(int j=0;j<CT;j++){ float v = acc[i][j][r]; ps += v*av[j]; pd += v*dv[j]; }
      #pragma unroll
      for(int mk=1; mk<16; mk<<=1){ ps+=__shfl_xor(ps,mk); pd+=__shfl_xor(pd,mk); }
      if(fr==0 && row < M){ as_o[row]=ps; ad_o[row]=pd; }
    }
  }
}

// ---------------- GEMM1: f32 A -> bf16 MFMA, Outbf[M x 64] = A[M x 512] @ W, fused att ----------------
#define BM 128
#define BK 32
#define LSTR 40
__global__ __launch_bounds__(256) void k_gemm1(const float* __restrict__ A, const unsigned short* __restrict__ Wt,
                                               const float* __restrict__ asv, const float* __restrict__ adv,
                                               unsigned short* __restrict__ Out,
                                               float* __restrict__ as_o, float* __restrict__ ad_o, int M){
  __shared__ __attribute__((aligned(16))) unsigned short Al[2][BM*LSTR];
  __shared__ __attribute__((aligned(16))) unsigned short Bl[2][64*LSTR];
  int t = threadIdx.x;
  int w = t >> 6, l = t & 63;
  int row0 = blockIdx.x * BM;

  int srow = t >> 1;
  int shalf = t & 1;
  int bn = t >> 2;
  int bseg = t & 3;

  int fr = l & 15, kg = l >> 4;

  frag_cd acc[2][4];
  #pragma unroll
  for(int i=0;i<2;i++)
    #pragma unroll
    for(int j=0;j<4;j++) acc[i][j] = (frag_cd){0.f,0.f,0.f,0.f};

  int rg = row0 + srow; if(rg >= M) rg = M-1;
  const float* aprow = &A[(size_t)rg*FIN + shalf*16];

  #define STAGE(buf, kc) do { \
    const float* ap = aprow + (kc); \
    float4 v0 = *(const float4*)(ap); \
    float4 v1 = *(const float4*)(ap+4); \
    float4 v2 = *(const float4*)(ap+8); \
    float4 v3 = *(const float4*)(ap+12); \
    uint4 pa, pb; \
    CVTPK(pa.x, v0.x, v0.y); CVTPK(pa.y, v0.z, v0.w); \
    CVTPK(pa.z, v1.x, v1.y); CVTPK(pa.w, v1.z, v1.w); \
    CVTPK(pb.x, v2.x, v2.y); CVTPK(pb.y, v2.z, v2.w); \
    CVTPK(pb.z, v3.x, v3.y); CVTPK(pb.w, v3.z, v3.w); \
    *(uint4*)&Al[buf][srow*LSTR + shalf*16] = pa; \
    *(uint4*)&Al[buf][srow*LSTR + shalf*16 + 8] = pb; \
    *(uint4*)&Bl[buf][bn*LSTR + bseg*8] = *(const uint4*)&Wt[bn*FIN + (kc) + bseg*8]; \
  } while(0)

  STAGE(0, 0);
  __syncthreads();

  #pragma unroll 1
  for(int step = 0; step < FIN/BK; ++step){
    int buf = step & 1;
    if(step + 1 < FIN/BK) STAGE(buf^1, (step+1)*BK);
    frag_ab af[2], bfr[4];
    #pragma unroll
    for(int i=0;i<2;i++) af[i] = *(const frag_ab*)&Al[buf][(w*32 + i*16 + fr)*LSTR + kg*8];
    #pragma unroll
    for(int j=0;j<4;j++) bfr[j] = *(const frag_ab*)&Bl[buf][(j*16 + fr)*LSTR + kg*8];
    #pragma unroll
    for(int i=0;i<2;i++)
      #pragma unroll
      for(int j=0;j<4;j++)
        acc[i][j] = __builtin_amdgcn_mfma_f32_16x16x32_bf16(af[i], bfr[j], acc[i][j], 0, 0, 0);
    __syncthreads();
  }

  #pragma unroll
  for(int i=0;i<2;i++){
    int crow = row0 + w*32 + i*16 + kg*4;
    #pragma unroll
    for(int j=0;j<4;j++){
      int ccol = j*16 + fr;
      #pragma unroll
      for(int r=0;r<4;r++){
        if(crow + r < M) Out[(size_t)(crow+r)*HDIM + ccol] = f2bf(acc[i][j][r]);
      }
    }
  }
  att_epi8(acc, row0 + w*32, fr, kg, asv, adv, as_o, ad_o, M);
  #undef STAGE
}

// ---------------- bf16 MFMA GEMM (layers 2,3) with fused att ----------------
template<int K, int C, int HEADS>
__global__ __launch_bounds__(256) void k_gemmb(const unsigned short* __restrict__ A,
                                               const unsigned short* __restrict__ Wt,
                                               const float* __restrict__ asv, const float* __restrict__ adv,
                                               unsigned short* __restrict__ Out,
                                               float* __restrict__ as_o, float* __restrict__ ad_o, int M){
  constexpr int CT = (C + 15)/16;
  __shared__ __attribute__((aligned(16))) unsigned short Al[2][BM*LSTR];
  __shared__ __attribute__((aligned(16))) unsigned short Bl[2][64*LSTR];
  int t = threadIdx.x;
  int w = t >> 6, l = t & 63;
  int row0 = blockIdx.x * BM;

  int srow = t >> 1;
  int shalf = t & 1;
  int bn = t >> 2;
  int bseg = t & 3;

  int fr = l & 15, kg = l >> 4;

  frag_cd acc[2][CT];
  #pragma unroll
  for(int i=0;i<2;i++)
    #pragma unroll
    for(int j=0;j<CT;j++) acc[i][j] = (frag_cd){0.f,0.f,0.f,0.f};

  int rg = row0 + srow; if(rg >= M) rg = M-1;
  const unsigned short* aprow = &A[(size_t)rg*K + shalf*16];

  #define STAGEB(buf, kc) do { \
    *(uint4*)&Al[buf][srow*LSTR + shalf*16]     = *(const uint4*)(aprow + (kc)); \
    *(uint4*)&Al[buf][srow*LSTR + shalf*16 + 8] = *(const uint4*)(aprow + (kc) + 8); \
    *(uint4*)&Bl[buf][bn*LSTR + bseg*8] = *(const uint4*)&Wt[bn*K + (kc) + bseg*8]; \
  } while(0)

  STAGEB(0, 0);
  __syncthreads();

  #pragma unroll 1
  for(int step = 0; step < K/BK; ++step){
    int buf = step & 1;
    if(step + 1 < K/BK) STAGEB(buf^1, (step+1)*BK);
    frag_ab af[2], bfr[CT];
    #pragma unroll
    for(int i=0;i<2;i++) af[i] = *(const frag_ab*)&Al[buf][(w*32 + i*16 + fr)*LSTR + kg*8];
    #pragma unroll
    for(int j=0;j<CT;j++) bfr[j] = *(const frag_ab*)&Bl[buf][(j*16 + fr)*LSTR + kg*8];
    #pragma unroll
    for(int i=0;i<2;i++)
      #pragma unroll
      for(int j=0;j<CT;j++)
        acc[i][j] = __builtin_amdgcn_mfma_f32_16x16x32_bf16(af[i], bfr[j], acc[i][j], 0, 0, 0);
    __syncthreads();
  }

  #pragma unroll
  for(int i=0;i<2;i++){
    int crow = row0 + w*32 + i*16 + kg*4;
    #pragma unroll
    for(int j=0;j<CT;j++){
      int ccol = j*16 + fr;
      if(ccol >= C) continue;
      #pragma unroll
      for(int r=0;r<4;r++){
        if(crow + r < M) Out[(size_t)(crow+r)*C + ccol] = f2bf(acc[i][j][r]);
      }
    }
  }
  if(HEADS == 8) att_epi8(acc, row0 + w*32, fr, kg, asv, adv, as_o, ad_o, M);
  else          att_epi1(acc, row0 + w*32, fr, kg, asv, adv, as_o, ad_o, M);
  #undef STAGEB
}

// ---------------- aggregation: 4 edges per wave, 4 bf16 features/lane ----------------
// as_/ad_ pre-scaled by log2e (leaky-relu is positively homogeneous -> softmax invariant, exp -> exp2).
// HEADS=8 as_/ad_ stored permuted: head hid at position (hid&1)*4 + (hid>>1).
template<int HEADS, int DIM, bool DO_ELU, bool DO_LSM>
__global__ __launch_bounds__(256) void k_agg(const unsigned short* __restrict__ hbf, const int* __restrict__ rp,
                      const int* __restrict__ col,
                      const float* __restrict__ as_, const float* __restrict__ ad_,
                      const float* __restrict__ bias, void* __restrict__ outp){
  int gid = blockIdx.x*256 + threadIdx.x;
  int node = gid >> 6, lane = gid & 63;
  if(node >= NN) return;
  constexpr int HD = HEADS*DIM;
  int el = lane >> 4;
  int fl = lane & 15;
  int f0 = fl*4;
  bool act = f0 < HD;
  int f0c = act ? f0 : 0;
  int hx = 0;
  if(HEADS == 8){ int hidx = f0 >> 3; hx = ((hidx&1)<<2) | (hidx>>1); }
  int beg = rp[node], end = rp[node+1];
  int deg = end - beg;
  float adn = ad_[node*HEADS + hx];
  float m = -1e38f, s = 0.f;
  float a0 = 0.f, a1 = 0.f, a2 = 0.f, a3 = 0.f;

  for(int base = 0; base < deg; base += 64){
    int cnt = deg - base; if(cnt > 64) cnt = 64;
    int idx = 0;
    if(lane < cnt) idx = col[beg + base + lane];
    int jf = cnt & ~7;
    int j = 0;
    for(; j < jf; j += 8){            // fully-valid groups: no masking
      int sn0 = __shfl(idx, j + el);
      int sn1 = __shfl(idx, j + 4 + el);
      float ea0 = as_[sn0*HEADS + hx];
      float ea1 = as_[sn1*HEADS + hx];
      uint2 h0 = *(const uint2*)&hbf[(size_t)sn0*HD + f0c];
      uint2 h1 = *(const uint2*)&hbf[(size_t)sn1*HD + f0c];
      float e0 = ea0 + adn; e0 = fmaxf(e0, 0.2f*e0);
      float e1 = ea1 + adn; e1 = fmaxf(e1, 0.2f*e1);
      float gm = fmaxf(fmaxf(e0, e1), m);
      float c  = exp2f(m - gm);
      float p0 = exp2f(e0 - gm);
      float p1 = exp2f(e1 - gm);
      s = s*c + p0 + p1;
      a0 = a0*c + p0*bflo(h0.x) + p1*bflo(h1.x);
      a1 = a1*c + p0*bfhi(h0.x) + p1*bfhi(h1.x);
      a2 = a2*c + p0*bflo(h0.y) + p1*bflo(h1.y);
      a3 = a3*c + p0*bfhi(h0.y) + p1*bfhi(h1.y);
      m = gm;
    }
    if(j < cnt){                      // masked tail group
      int sn0 = __shfl(idx, j + el);
      int sn1 = __shfl(idx, j + 4 + el);
      bool v0 = (j + el) < cnt;
      bool v1 = (j + 4 + el) < cnt;
      float ea0 = as_[sn0*HEADS + hx];
      float ea1 = as_[sn1*HEADS + hx];
      uint2 h0 = *(const uint2*)&hbf[(size_t)sn0*HD + f0c];
      uint2 h1 = *(const uint2*)&hbf[(size_t)sn1*HD + f0c];
      float e0 = ea0 + adn; e0 = fmaxf(e0, 0.2f*e0); e0 = v0 ? e0 : -INFINITY;
      float e1 = ea1 + adn; e1 = fmaxf(e1, 0.2f*e1); e1 = v1 ? e1 : -INFINITY;
      float gm = fmaxf(fmaxf(e0, e1), m);
      float c  = exp2f(m - gm);
      float p0 = exp2f(e0 - gm);
      float p1 = exp2f(e1 - gm);
      s = s*c + p0 + p1;
      a0 = a0*c + p0*bflo(h0.x) + p1*bflo(h1.x);
      a1 = a1*c + p0*bfhi(h0.x) + p1*bfhi(h1.x);
      a2 = a2*c + p0*bflo(h0.y) + p1*bflo(h1.y);
      a3 = a3*c + p0*bfhi(h0.y) + p1*bfhi(h1.y);
      m = gm;
    }
  }

  // merge the 4 quarter-wave softmax states
  #pragma unroll
  for(int wd=16; wd<=32; wd<<=1){
    float mo  = __shfl_xor(m, wd);
    float so  = __shfl_xor(s, wd);
    float b0  = __shfl_xor(a0, wd);
    float b1  = __shfl_xor(a1, wd);
    float b2  = __shfl_xor(a2, wd);
    float b3  = __shfl_xor(a3, wd);
    float mm2 = fmaxf(m, mo);
    float cs  = exp2f(m - mm2), co = exp2f(mo - mm2);
    s  = s*cs  + so*co;
    a0 = a0*cs + b0*co;
    a1 = a1*cs + b1*co;
    a2 = a2*cs + b2*co;
    a3 = a3*cs + b3*co;
    m = mm2;
  }

  float inv = 1.f/s;
  float o0 = a0*inv, o1 = a1*inv, o2 = a2*inv, o3 = a3*inv;
  if(act){
    float4 bb = *(const float4*)&bias[f0];
    o0 += bb.x; o1 += bb.y; o2 += bb.z; o3 += bb.w;
  }
  if(DO_ELU){
    o0 = (o0 > 0.f) ? o0 : expm1f(o0);
    o1 = (o1 > 0.f) ? o1 : expm1f(o1);
    o2 = (o2 > 0.f) ? o2 : expm1f(o2);
    o3 = (o3 > 0.f) ? o3 : expm1f(o3);
  }
  if(!DO_LSM){
    if(act && el == 0){
      unsigned short* ob = (unsigned short*)outp;
      unsigned plo, phi;
      CVTPK(plo, o0, o1);
      CVTPK(phi, o2, o3);
      uint2 pk; pk.x = plo; pk.y = phi;
      *(uint2*)&ob[(size_t)node*HD + f0] = pk;
    }
  } else {
    float vmax = act ? fmaxf(fmaxf(o0,o1), fmaxf(o2,o3)) : -INFINITY;
    #pragma unroll
    for(int mm2=1; mm2<16; mm2<<=1) vmax = fmaxf(vmax, __shfl_xor(vmax, mm2));
    float ex = act ? (expf(o0-vmax) + expf(o1-vmax) + expf(o2-vmax) + expf(o3-vmax)) : 0.f;
    #pragma unroll
    for(int mm2=1; mm2<16; mm2<<=1) ex += __shfl_xor(ex, mm2);
    float lg = logf(ex);
    if(act && el == 0){
      float* of = (float*)outp;
      float4 r;
      r.x = o0 - vmax - lg; r.y = o1 - vmax - lg;
      r.z = o2 - vmax - lg; r.w = o3 - vmax - lg;
      *(float4*)&of[(size_t)node*HD + f0] = r;
    }
  }
}

// ---------------- launch ----------------
static inline size_t alignup(size_t x){ return (x + 255) & ~(size_t)255; }

extern "C" void kernel_launch(void* const* d_in, const int* in_sizes, int n_in,
                              void* d_out, int out_size, void* d_ws, size_t ws_size,
                              hipStream_t stream){
  const float* x      = (const float*)d_in[0];
  const int*   ei     = (const int*)d_in[1];
  const float* W1     = (const float*)d_in[2];
  const float* asrc1  = (const float*)d_in[3];
  const float* adst1  = (const float*)d_in[4];
  const float* b1     = (const float*)d_in[5];
  const float* W2     = (const float*)d_in[6];
  const float* asrc2  = (const float*)d_in[7];
  const float* adst2  = (const float*)d_in[8];
  const float* b2     = (const float*)d_in[9];
  const float* W3     = (const float*)d_in[10];
  const float* asrc3  = (const float*)d_in[11];
  const float* adst3  = (const float*)d_in[12];
  const float* b3     = (const float*)d_in[13];
  const int* src = ei;
  const int* dst = ei + EE;

  char* w = (char*)d_ws;
  int* rp     = (int*)w;              w += alignup((size_t)(NN+1)*4);
  int* bbase  = (int*)w;              w += alignup((size_t)(NBUK+1)*4);
  int* bcur   = (int*)w;              w += alignup((size_t)NBUK*4);
  unsigned short* Wt1 = (unsigned short*)w; w += alignup((size_t)64*FIN*2);
  unsigned short* Wt2 = (unsigned short*)w; w += alignup((size_t)64*HDIM*2);
  unsigned short* Wt3 = (unsigned short*)w; w += alignup((size_t)64*HDIM*2);
  float* attv = (float*)w;            w += alignup((size_t)352*4);
  int* col    = (int*)w;              w += alignup((size_t)ET*4);
  int* pbuf   = (int*)w;              w += alignup((size_t)NBUK*CAP*4);
  unsigned short* hAb = (unsigned short*)w; w += alignup((size_t)NN*HDIM*2 + 256);
  unsigned short* hBb = (unsigned short*)w; w += alignup((size_t)NN*HDIM*2 + 256);
  unsigned short* hCb = (unsigned short*)w; w += alignup((size_t)NN*NCLS*2 + 256);
  float* asA  = (float*)w;            w += alignup((size_t)NN*8*4);
  float* adA  = (float*)w;            w += alignup((size_t)NN*8*4);

  dim3 blk(256);
  int gWav  = (NN*64 + 255)/256;
  int gG1   = (NN + BM - 1)/BM;
  int gBuk  = (ET + EPB - 1)/EPB;

  // prep (weights, scaled att vecs, zero bcur)
  k_prep<<<(41312 + 255)/256, blk, 0, stream>>>(W1, W2, W3, asrc1, adst1, asrc2, adst2, asrc3, adst3,
                                                Wt1, Wt2, Wt3, attv, bcur);
  // CSR build
  k_bucket<<<gBuk, blk, 0, stream>>>(src, dst, bcur, pbuf);
  k_bscan<<<1, dim3(NBUK), 0, stream>>>(bcur, bbase);
  k_bfinal<<<NBUK_USED, blk, 0, stream>>>(bbase, pbuf, rp, col);

  // layer 1
  k_gemm1<<<gG1, blk, 0, stream>>>(x, Wt1, attv + 0, attv + 64, hAb, asA, adA, NN);
  k_agg<8,8,true,false><<<gWav, blk, 0, stream>>>(hAb, rp, col, asA, adA, b1, hBb);

  // layer 2
  k_gemmb<HDIM, HDIM, 8><<<gG1, blk, 0, stream>>>(hBb, Wt2, attv + 128, attv + 192, hAb, asA, adA, NN);
  k_agg<8,8,true,false><<<gWav, blk, 0, stream>>>(hAb, rp, col, asA, adA, b2, hBb);

  // layer 3
  k_gemmb<HDIM, NCLS, 1><<<gG1, blk, 0, stream>>>(hBb, Wt3, attv + 256, attv + 304, hCb, asA, adA, NN);
  k_agg<1,NCLS,false,true><<<gWav, blk, 0, stream>>>(hCb, rp, col, asA, adA, b3, d_out);
}